// Round 4
// baseline (2392.472 us; speedup 1.0000x reference)
//
#include <hip/hip_runtime.h>
#include <hip/hip_bf16.h>
#include <hip/hip_fp16.h>

#define HID 128
#define BIN_T 8192
#define NBMAX 1664   // max 64-node buckets (N <= 106496)

// ---------------- degree ----------------

__global__ void k_count_deg(const int* __restrict__ dst, int* __restrict__ deg, int E) {
    int e = blockIdx.x * blockDim.x + threadIdx.x;
    if (e < E) atomicAdd(&deg[dst[e]], 1);
}

__global__ void k_deg_finalize(const int* __restrict__ deg, float* __restrict__ dinv,
                               float* __restrict__ invd, int N) {
    int i = blockIdx.x * blockDim.x + threadIdx.x;
    if (i < N) {
        float d = (float)deg[i] + 1.0f;   // +1 self loop
        dinv[i] = 1.0f / sqrtf(d);
        invd[i] = 1.0f / d;
    }
}

// bcount[b] = sum of deg over bucket b (64 nodes)
__global__ void k_bucket_sum(const int* __restrict__ deg, int* __restrict__ bcount,
                             int N, int NB) {
    int b = blockIdx.x * blockDim.x + threadIdx.x;
    if (b >= NB) return;
    int base = b * 64, end = min(base + 64, N);
    int s = 0;
    for (int i = base; i < end; ++i) s += deg[i];
    bcount[b] = s;
}

// single-block exclusive scan over NB buckets -> boff, bcursor
__global__ void k_bucket_scan(const int* __restrict__ bcount, int* __restrict__ boff,
                              int* __restrict__ bcursor, int NB) {
    __shared__ int tt[256];
    int ts = threadIdx.x;
    int b0 = ts * 7;
    int loc[7]; int run = 0;
    #pragma unroll
    for (int k = 0; k < 7; ++k) {
        int b = b0 + k;
        int c = (b < NB) ? bcount[b] : 0;
        loc[k] = run; run += c;
    }
    tt[ts] = run;
    __syncthreads();
    int val = run;
    for (int off = 1; off < 256; off <<= 1) {
        int add = (ts >= off) ? tt[ts - off] : 0;
        __syncthreads();
        tt[ts] += add;
        __syncthreads();
    }
    int ebase = tt[ts] - val;
    #pragma unroll
    for (int k = 0; k < 7; ++k) {
        int b = b0 + k;
        if (b < NB) { boff[b] = ebase + loc[k]; bcursor[b] = ebase + loc[k]; }
    }
    if (ts == 255) boff[NB] = tt[255];
}

// ---------------- tile-sorted bucket binning ----------------
// pairs[slot] = src | (dst&63)<<26, grouped by bucket (dst>>6), coalesced writes.

__global__ void k_tile_bin(const int* __restrict__ src, const int* __restrict__ dst,
                           int* __restrict__ bcursor, unsigned int* __restrict__ pairs,
                           int E, int NB) {
    __shared__ unsigned int dbuf[BIN_T];
    __shared__ unsigned short perm[BIN_T];
    __shared__ int hist[NBMAX];
    __shared__ int lbase[NBMAX];
    __shared__ int gbase[NBMAX];
    __shared__ int tt[256];
    int t = threadIdx.x;
    int tilebase = blockIdx.x * BIN_T;
    int n = min(BIN_T, E - tilebase);
    for (int i = t; i < NB; i += 256) hist[i] = 0;
    __syncthreads();
    for (int i = t; i < n; i += 256) {
        unsigned int d = (unsigned int)dst[tilebase + i];
        dbuf[i] = d;
        atomicAdd(&hist[d >> 6], 1);
    }
    __syncthreads();
    // exclusive scan hist -> lbase
    {
        int b0 = t * 7, loc[7], run = 0;
        #pragma unroll
        for (int k = 0; k < 7; ++k) {
            int b = b0 + k;
            int c = (b < NB) ? hist[b] : 0;
            loc[k] = run; run += c;
        }
        tt[t] = run;
        __syncthreads();
        int val = run;
        for (int off = 1; off < 256; off <<= 1) {
            int add = (t >= off) ? tt[t - off] : 0;
            __syncthreads();
            tt[t] += add;
            __syncthreads();
        }
        int ebase = tt[t] - val;
        #pragma unroll
        for (int k = 0; k < 7; ++k) {
            int b = b0 + k;
            if (b < NB) lbase[b] = ebase + loc[k];
        }
    }
    __syncthreads();
    // claim global slots per bucket
    for (int i = t; i < NB; i += 256) {
        int c = hist[i];
        gbase[i] = (c > 0) ? atomicAdd(&bcursor[i], c) : 0;
    }
    __syncthreads();
    for (int i = t; i < NB; i += 256) hist[i] = lbase[i];
    __syncthreads();
    // scatter into bucket-sorted local order
    for (int i = t; i < n; i += 256) {
        int b = (int)(dbuf[i] >> 6);
        int p = atomicAdd(&hist[b], 1);
        perm[p] = (unsigned short)i;
    }
    __syncthreads();
    // coalesced output
    for (int p = t; p < n; p += 256) {
        int li = perm[p];
        unsigned int d = dbuf[li];
        int b = (int)(d >> 6);
        int addr = gbase[b] + (p - lbase[b]);
        pairs[addr] = (unsigned int)src[tilebase + li] | ((d & 63u) << 26);
    }
}

// ---------------- layer-1 aggregation (24-dim input space), per-bucket ----------------

__global__ void k_agg23_b(const unsigned int* __restrict__ pairs, const int* __restrict__ boff,
                          const int* __restrict__ residue, const float* __restrict__ pos,
                          const float* __restrict__ dinv, const float* __restrict__ invd,
                          float* __restrict__ z0, int N) {
    __shared__ float acc[64][25];
    int t = threadIdx.x, b = blockIdx.x;
    for (int q = t; q < 64 * 25; q += 256) ((float*)acc)[q] = 0.f;
    __syncthreads();
    int lo = boff[b], hi = boff[b + 1];
    for (int e = lo + t; e < hi; e += 256) {
        unsigned int pk = pairs[e];
        int s = (int)(pk & 0x3FFFFFFu), dl = (int)(pk >> 26);
        float w = dinv[s];
        atomicAdd(&acc[dl][residue[s]], w);
        atomicAdd(&acc[dl][20], w * pos[s * 3 + 0]);
        atomicAdd(&acc[dl][21], w * pos[s * 3 + 1]);
        atomicAdd(&acc[dl][22], w * pos[s * 3 + 2]);
    }
    __syncthreads();
    int base = b * 64;
    for (int q = t; q < 64 * 24; q += 256) {
        int dl = q / 24, k = q - dl * 24;
        int node = base + dl;
        if (node >= N) continue;
        float v = acc[dl][k] * dinv[node];
        float ii = invd[node];
        if (k == residue[node]) v += ii;
        if (k >= 20 && k < 23) v += ii * pos[node * 3 + (k - 20)];
        z0[(size_t)node * 24 + k] = v;
    }
}

// x1 = relu(z0 @ W[23,128] + b), stored fp16
#define G24_ROWS 32
__global__ void k_gemm24(const float* __restrict__ z0, const float* __restrict__ W,
                         const float* __restrict__ b, __half* __restrict__ x1h, int N) {
    __shared__ float Ws[23 * 128];
    __shared__ float zr[G24_ROWS][25];
    int t = threadIdx.x;
    for (int q = t; q < 23 * 128; q += 256) Ws[q] = W[q];
    int blockbase = blockIdx.x * G24_ROWS;
    for (int q = t; q < G24_ROWS * 24; q += 256) {
        int row = q / 24, k = q - row * 24;
        int gn = blockbase + row;
        zr[row][k] = (gn < N) ? z0[(size_t)gn * 24 + k] : 0.f;
    }
    __syncthreads();
    int j = t & 127, slot = t >> 7;
    float bj = b[j];
    for (int r = slot; r < G24_ROWS; r += 2) {
        int gn = blockbase + r;
        if (gn >= N) break;
        float acc = bj;
        #pragma unroll
        for (int k = 0; k < 23; ++k) acc += zr[r][k] * Ws[k * 128 + j];
        x1h[(size_t)gn * HID + j] = __float2half(fmaxf(acc, 0.f));
    }
}

// ---------------- layer-2 aggregation per-bucket, fp16 gather, LDS accumulate ----------------

__global__ void k_agg128_b(const __half2* __restrict__ x1h, const unsigned int* __restrict__ pairs,
                           const int* __restrict__ boff, const float* __restrict__ dinv,
                           const float* __restrict__ invd, float* __restrict__ z, int N) {
    __shared__ float acc[64][128];
    int t = threadIdx.x, b = blockIdx.x;
    int lane = t & 63, wave = t >> 6;
    for (int q = t; q < 64 * 128 / 4; q += 256) ((float4*)&acc[0][0])[q] = float4{0, 0, 0, 0};
    __syncthreads();
    int lo = boff[b], hi = boff[b + 1];
    for (int e = lo + wave; e < hi; e += 8) {   // 2 edges per iter for MLP
        unsigned int pk0 = pairs[e];
        bool has1 = (e + 4) < hi;
        unsigned int pk1 = has1 ? pairs[e + 4] : pk0;
        int s0 = (int)(pk0 & 0x3FFFFFFu), dl0 = (int)(pk0 >> 26);
        int s1 = (int)(pk1 & 0x3FFFFFFu), dl1 = (int)(pk1 >> 26);
        float w0 = dinv[s0], w1 = dinv[s1];
        __half2 h0 = x1h[(size_t)s0 * 64 + lane];
        __half2 h1 = x1h[(size_t)s1 * 64 + lane];
        float2 v0 = __half22float2(h0);
        float2 v1 = __half22float2(h1);
        atomicAdd(&acc[dl0][lane * 2],     v0.x * w0);
        atomicAdd(&acc[dl0][lane * 2 + 1], v0.y * w0);
        if (has1) {
            atomicAdd(&acc[dl1][lane * 2],     v1.x * w1);
            atomicAdd(&acc[dl1][lane * 2 + 1], v1.y * w1);
        }
    }
    __syncthreads();
    int base = b * 64;
    const __half* x1s = (const __half*)x1h;
    for (int q = t; q < 64 * 128; q += 256) {
        int dl = q >> 7, c = q & 127;
        int node = base + dl;
        if (node < N) {
            float self = __half2float(x1s[(size_t)node * 128 + c]);
            z[(size_t)node * 128 + c] = acc[dl][c] * dinv[node] + invd[node] * self;
        }
    }
}

// ---------------- protein layer-2 gemm fused with mean-pool sum ----------------

__global__ void k_gemm_pool(const float* __restrict__ Z, const float* __restrict__ W,
                            const float* __restrict__ b, const int* __restrict__ batch,
                            float* __restrict__ psum, int N) {
    __shared__ float red[8][128];
    int tile = blockIdx.x * 32;
    int cg = threadIdx.x & 31, rg = threadIdx.x >> 5;
    int j0 = cg * 4;
    int r[4]; bool val[4];
    #pragma unroll
    for (int m = 0; m < 4; ++m) {
        int rr = tile + rg * 4 + m;
        val[m] = rr < N;
        r[m] = val[m] ? rr : (N - 1);
    }
    float acc[4][4] = {};
    for (int k4 = 0; k4 < 32; ++k4) {
        int k = k4 * 4;
        float4 w0 = *(const float4*)&W[(k + 0) * HID + j0];
        float4 w1 = *(const float4*)&W[(k + 1) * HID + j0];
        float4 w2 = *(const float4*)&W[(k + 2) * HID + j0];
        float4 w3 = *(const float4*)&W[(k + 3) * HID + j0];
        #pragma unroll
        for (int m = 0; m < 4; ++m) {
            float4 x = *(const float4*)&Z[(size_t)r[m] * HID + k];
            acc[m][0] += x.x * w0.x + x.y * w1.x + x.z * w2.x + x.w * w3.x;
            acc[m][1] += x.x * w0.y + x.y * w1.y + x.z * w2.y + x.w * w3.y;
            acc[m][2] += x.x * w0.z + x.y * w1.z + x.z * w2.z + x.w * w3.z;
            acc[m][3] += x.x * w0.w + x.y * w1.w + x.z * w2.w + x.w * w3.w;
        }
    }
    float4 bb = *(const float4*)&b[j0];
    float bbv[4] = {bb.x, bb.y, bb.z, bb.w};
    float v[4][4];
    #pragma unroll
    for (int m = 0; m < 4; ++m)
        #pragma unroll
        for (int c = 0; c < 4; ++c)
            v[m][c] = fmaxf(acc[m][c] + bbv[c], 0.f);

    int gfirst = batch[tile];
    int glast = batch[min(tile + 31, N - 1)];
    if (gfirst == glast) {
        float s0 = 0.f, s1 = 0.f, s2 = 0.f, s3 = 0.f;
        #pragma unroll
        for (int m = 0; m < 4; ++m) if (val[m]) {
            s0 += v[m][0]; s1 += v[m][1]; s2 += v[m][2]; s3 += v[m][3];
        }
        *(float4*)&red[rg][j0] = make_float4(s0, s1, s2, s3);
        __syncthreads();
        if (threadIdx.x < 128) {
            float tot = 0.f;
            #pragma unroll
            for (int q = 0; q < 8; ++q) tot += red[q][threadIdx.x];
            atomicAdd(&psum[gfirst * HID + threadIdx.x], tot);
        }
    } else {
        #pragma unroll
        for (int m = 0; m < 4; ++m) if (val[m]) {
            int g = batch[r[m]];
            #pragma unroll
            for (int c = 0; c < 4; ++c)
                atomicAdd(&psum[g * HID + j0 + c], v[m][c]);
        }
    }
}

__global__ void k_count_batch(const int* __restrict__ batch, int* __restrict__ pcnt, int N) {
    __shared__ int h[64];
    if (threadIdx.x < 64) h[threadIdx.x] = 0;
    __syncthreads();
    for (int i = blockIdx.x * blockDim.x + threadIdx.x; i < N; i += gridDim.x * blockDim.x)
        atomicAdd(&h[batch[i]], 1);
    __syncthreads();
    if (threadIdx.x < 64 && h[threadIdx.x] > 0)
        atomicAdd(&pcnt[threadIdx.x], h[threadIdx.x]);
}

// ctxW[g] = (psum[g]/cnt[g]) @ W1[128:,:] + b1
__global__ void k_ctxw_div(const float* __restrict__ psum, const int* __restrict__ pcnt,
                           const float* __restrict__ W1, const float* __restrict__ b1,
                           float* __restrict__ ctxW) {
    __shared__ float pr[128];
    int g = blockIdx.x, j = threadIdx.x;
    pr[j] = psum[g * HID + j] / fmaxf((float)pcnt[g], 1.f);
    __syncthreads();
    float a = b1[j];
    #pragma unroll 4
    for (int k = 0; k < HID; ++k) a += pr[k] * W1[(HID + k) * HID + j];
    ctxW[g * HID + j] = a;
}

// ---------------- mm layer-2 gemm fused with head ----------------

__global__ void k_mm_tail(const float* __restrict__ Z, const float* __restrict__ Wm2,
                          const float* __restrict__ bm2, const int* __restrict__ batch,
                          const float* __restrict__ ctxW, const float* __restrict__ W1,
                          const float* __restrict__ W2, const float* __restrict__ b2,
                          float* __restrict__ out, int N) {
    __shared__ float Xs[32][132];
    __shared__ float Hs[32][132];
    int tile = blockIdx.x * 32;
    int cg = threadIdx.x & 31, rg = threadIdx.x >> 5;
    int j0 = cg * 4;
    int r[4]; bool val[4];
    #pragma unroll
    for (int m = 0; m < 4; ++m) {
        int rr = tile + rg * 4 + m;
        val[m] = rr < N;
        r[m] = val[m] ? rr : (N - 1);
    }
    // phase 1: x2 tile
    {
        float acc[4][4] = {};
        for (int k4 = 0; k4 < 32; ++k4) {
            int k = k4 * 4;
            float4 w0 = *(const float4*)&Wm2[(k + 0) * HID + j0];
            float4 w1 = *(const float4*)&Wm2[(k + 1) * HID + j0];
            float4 w2 = *(const float4*)&Wm2[(k + 2) * HID + j0];
            float4 w3 = *(const float4*)&Wm2[(k + 3) * HID + j0];
            #pragma unroll
            for (int m = 0; m < 4; ++m) {
                float4 x = *(const float4*)&Z[(size_t)r[m] * HID + k];
                acc[m][0] += x.x * w0.x + x.y * w1.x + x.z * w2.x + x.w * w3.x;
                acc[m][1] += x.x * w0.y + x.y * w1.y + x.z * w2.y + x.w * w3.y;
                acc[m][2] += x.x * w0.z + x.y * w1.z + x.z * w2.z + x.w * w3.z;
                acc[m][3] += x.x * w0.w + x.y * w1.w + x.z * w2.w + x.w * w3.w;
            }
        }
        float4 bb = *(const float4*)&bm2[j0];
        float bbv[4] = {bb.x, bb.y, bb.z, bb.w};
        #pragma unroll
        for (int m = 0; m < 4; ++m) {
            int row = rg * 4 + m;
            *(float4*)&Xs[row][j0] = make_float4(
                fmaxf(acc[m][0] + bbv[0], 0.f), fmaxf(acc[m][1] + bbv[1], 0.f),
                fmaxf(acc[m][2] + bbv[2], 0.f), fmaxf(acc[m][3] + bbv[3], 0.f));
        }
    }
    __syncthreads();
    // phase 2: h tile
    {
        float acc[4][4] = {};
        for (int k4 = 0; k4 < 32; ++k4) {
            int k = k4 * 4;
            float4 w0 = *(const float4*)&W1[(k + 0) * HID + j0];
            float4 w1 = *(const float4*)&W1[(k + 1) * HID + j0];
            float4 w2 = *(const float4*)&W1[(k + 2) * HID + j0];
            float4 w3 = *(const float4*)&W1[(k + 3) * HID + j0];
            #pragma unroll
            for (int m = 0; m < 4; ++m) {
                float4 x = *(const float4*)&Xs[rg * 4 + m][k];
                acc[m][0] += x.x * w0.x + x.y * w1.x + x.z * w2.x + x.w * w3.x;
                acc[m][1] += x.x * w0.y + x.y * w1.y + x.z * w2.y + x.w * w3.y;
                acc[m][2] += x.x * w0.z + x.y * w1.z + x.z * w2.z + x.w * w3.z;
                acc[m][3] += x.x * w0.w + x.y * w1.w + x.z * w2.w + x.w * w3.w;
            }
        }
        #pragma unroll
        for (int m = 0; m < 4; ++m) {
            int g = batch[r[m]];
            float4 cx = *(const float4*)&ctxW[g * HID + j0];
            float cxv[4] = {cx.x, cx.y, cx.z, cx.w};
            int row = rg * 4 + m;
            *(float4*)&Hs[row][j0] = make_float4(
                fmaxf(acc[m][0] + cxv[0], 0.f), fmaxf(acc[m][1] + cxv[1], 0.f),
                fmaxf(acc[m][2] + cxv[2], 0.f), fmaxf(acc[m][3] + cxv[3], 0.f));
        }
    }
    __syncthreads();
    // phase 3: out = h @ W2 + b2
    {
        int row = threadIdx.x >> 3, seg = threadIdx.x & 7;
        float p0 = 0.f, p1 = 0.f, p2 = 0.f;
        #pragma unroll
        for (int kk = 0; kk < 16; ++kk) {
            int k = seg * 16 + kk;
            float hv = Hs[row][k];
            p0 += hv * W2[k * 3 + 0];
            p1 += hv * W2[k * 3 + 1];
            p2 += hv * W2[k * 3 + 2];
        }
        __syncthreads();
        Xs[row][seg * 3 + 0] = p0;
        Xs[row][seg * 3 + 1] = p1;
        Xs[row][seg * 3 + 2] = p2;
        __syncthreads();
        if (threadIdx.x < 96) {
            int rw = threadIdx.x / 3, c = threadIdx.x - rw * 3;
            int gr = tile + rw;
            if (gr < N) {
                float a = b2[c];
                #pragma unroll
                for (int q = 0; q < 8; ++q) a += Xs[rw][q * 3 + c];
                out[(size_t)gr * 3 + c] = a;
            }
        }
    }
}

// ---------------- launch ----------------

extern "C" void kernel_launch(void* const* d_in, const int* in_sizes, int n_in,
                              void* d_out, int out_size, void* d_ws, size_t ws_size,
                              hipStream_t stream) {
    const int*   residue_p = (const int*)d_in[0];
    const float* pos_p     = (const float*)d_in[1];
    const int*   ei_p      = (const int*)d_in[2];
    const int*   batch_p   = (const int*)d_in[3];
    const int*   residue_m = (const int*)d_in[4];
    const float* pos_m     = (const float*)d_in[5];
    const int*   ei_m      = (const int*)d_in[6];
    const int*   batch_m   = (const int*)d_in[7];
    const float* W_p1 = (const float*)d_in[8];
    const float* b_p1 = (const float*)d_in[9];
    const float* W_p2 = (const float*)d_in[10];
    const float* b_p2 = (const float*)d_in[11];
    const float* W_m1 = (const float*)d_in[12];
    const float* b_m1 = (const float*)d_in[13];
    const float* W_m2 = (const float*)d_in[14];
    const float* b_m2 = (const float*)d_in[15];
    const float* W1   = (const float*)d_in[16];
    const float* b1   = (const float*)d_in[17];
    const float* W2   = (const float*)d_in[18];
    const float* b2   = (const float*)d_in[19];

    const int N_P = in_sizes[0];
    const int E_P = in_sizes[2] / 2;
    const int N_M = in_sizes[4];
    const int E_M = in_sizes[6] / 2;
    const int G = 64;

    char* ws = (char*)d_ws;
    size_t off = 0;
    auto alloc = [&](size_t bytes) {
        char* p = ws + off;
        off += (bytes + 511) & ~size_t(511);
        return p;
    };
    float*        bufA    = (float*)alloc((size_t)N_P * HID * 4);   // z (fp32)
    float*        bufB    = (float*)alloc((size_t)N_P * 24 * 4);    // z0
    __half*       x1h     = (__half*)alloc((size_t)N_P * HID * 2);  // x1 fp16
    int*          deg     = (int*)  alloc((size_t)N_P * 4);
    float*        dinv    = (float*)alloc((size_t)N_P * 4);
    float*        invd    = (float*)alloc((size_t)N_P * 4);
    int*          bcount  = (int*)  alloc((NBMAX + 1) * 4);
    int*          boff    = (int*)  alloc((NBMAX + 1) * 4);
    int*          bcursor = (int*)  alloc((NBMAX + 1) * 4);
    unsigned int* pairs   = (unsigned int*)alloc((size_t)E_P * 4);
    float*        psum    = (float*)alloc((size_t)G * HID * 4);
    int*          pcnt    = (int*)  alloc((size_t)G * 4);
    float*        ctxW    = (float*)alloc((size_t)G * HID * 4);

    auto run_branch = [&](const int* residue, const float* pos, const int* ei,
                          const float* Wl1, const float* bl1, int N, int E) {
        const int* srcp = ei;
        const int* dstp = ei + E;
        int NB = (N + 63) / 64;

        hipMemsetAsync(deg, 0, (size_t)N * 4, stream);
        k_count_deg<<<(E + 255) / 256, 256, 0, stream>>>(dstp, deg, E);
        k_deg_finalize<<<(N + 255) / 256, 256, 0, stream>>>(deg, dinv, invd, N);
        k_bucket_sum<<<(NB + 255) / 256, 256, 0, stream>>>(deg, bcount, N, NB);
        k_bucket_scan<<<1, 256, 0, stream>>>(bcount, boff, bcursor, NB);
        k_tile_bin<<<(E + BIN_T - 1) / BIN_T, 256, 0, stream>>>(srcp, dstp, bcursor, pairs, E, NB);

        k_agg23_b<<<NB, 256, 0, stream>>>(pairs, boff, residue, pos, dinv, invd, bufB, N);
        k_gemm24<<<(N + G24_ROWS - 1) / G24_ROWS, 256, 0, stream>>>(bufB, Wl1, bl1, x1h, N);
        k_agg128_b<<<NB, 256, 0, stream>>>((const __half2*)x1h, pairs, boff, dinv, invd, bufA, N);
        // result: bufA (z, fp32)
    };

    // ---- protein branch ----
    run_branch(residue_p, pos_p, ei_p, W_p1, b_p1, N_P, E_P);
    hipMemsetAsync(psum, 0, (size_t)G * HID * 4, stream);
    hipMemsetAsync(pcnt, 0, (size_t)G * 4, stream);
    k_gemm_pool<<<(N_P + 31) / 32, 256, 0, stream>>>(bufA, W_p2, b_p2, batch_p, psum, N_P);
    k_count_batch<<<256, 256, 0, stream>>>(batch_p, pcnt, N_P);
    k_ctxw_div<<<G, HID, 0, stream>>>(psum, pcnt, W1, b1, ctxW);

    // ---- micromolecule branch ----
    run_branch(residue_m, pos_m, ei_m, W_m1, b_m1, N_M, E_M);
    k_mm_tail<<<(N_M + 31) / 32, 256, 0, stream>>>(bufA, W_m2, b_m2, batch_m, ctxW,
                                                   W1, W2, b2, (float*)d_out, N_M);
}

// Round 5
// 644.610 us; speedup vs baseline: 3.7115x; 3.7115x over previous
//
#include <hip/hip_runtime.h>
#include <hip/hip_bf16.h>
#include <hip/hip_fp16.h>

#define HID 128
#define BIN_T 8192
#define NBMAX 1664   // max 64-node buckets (N <= 106496)

// ---------------- degree ----------------

__global__ void k_count_deg(const int* __restrict__ dst, int* __restrict__ deg, int E) {
    int e = blockIdx.x * blockDim.x + threadIdx.x;
    if (e < E) atomicAdd(&deg[dst[e]], 1);
}

__global__ void k_deg_finalize(const int* __restrict__ deg, float* __restrict__ dinv,
                               float* __restrict__ invd, int N) {
    int i = blockIdx.x * blockDim.x + threadIdx.x;
    if (i < N) {
        float d = (float)deg[i] + 1.0f;   // +1 self loop
        dinv[i] = 1.0f / sqrtf(d);
        invd[i] = 1.0f / d;
    }
}

// ---------------- exclusive scan (deg -> rowptr) ----------------

#define SCAN_TPB 256
#define SCAN_VPT 4
#define SCAN_BS (SCAN_TPB * SCAN_VPT)

__global__ void k_scan_partial(const int* __restrict__ deg, int* __restrict__ partials, int N) {
    __shared__ int lds[SCAN_TPB];
    int base = blockIdx.x * SCAN_BS + threadIdx.x * SCAN_VPT;
    int s = 0;
    #pragma unroll
    for (int c = 0; c < SCAN_VPT; ++c) { int idx = base + c; if (idx < N) s += deg[idx]; }
    lds[threadIdx.x] = s;
    __syncthreads();
    for (int off = SCAN_TPB / 2; off > 0; off >>= 1) {
        if (threadIdx.x < off) lds[threadIdx.x] += lds[threadIdx.x + off];
        __syncthreads();
    }
    if (threadIdx.x == 0) partials[blockIdx.x] = lds[0];
}

__global__ void k_scan_root(int* __restrict__ partials, int nb) {
    __shared__ int lds[SCAN_TPB];
    int t = threadIdx.x;
    int v = (t < nb) ? partials[t] : 0;
    lds[t] = v;
    __syncthreads();
    for (int off = 1; off < SCAN_TPB; off <<= 1) {
        int add = (t >= off) ? lds[t - off] : 0;
        __syncthreads();
        lds[t] += add;
        __syncthreads();
    }
    if (t < nb) partials[t] = lds[t] - v;   // exclusive
}

__global__ void k_scan_final(const int* __restrict__ deg, const int* __restrict__ partials,
                             int* __restrict__ rowptr, int N) {
    __shared__ int lds[SCAN_TPB];
    int base = blockIdx.x * SCAN_BS + threadIdx.x * SCAN_VPT;
    int c0 = 0, c1 = 0, c2 = 0, c3 = 0;
    if (base + 0 < N) c0 = deg[base + 0];
    if (base + 1 < N) c1 = deg[base + 1];
    if (base + 2 < N) c2 = deg[base + 2];
    if (base + 3 < N) c3 = deg[base + 3];
    int s = c0 + c1 + c2 + c3;
    lds[threadIdx.x] = s;
    __syncthreads();
    for (int off = 1; off < SCAN_TPB; off <<= 1) {
        int add = (threadIdx.x >= off) ? lds[threadIdx.x - off] : 0;
        __syncthreads();
        lds[threadIdx.x] += add;
        __syncthreads();
    }
    int off = lds[threadIdx.x] - s + partials[blockIdx.x];
    if (base + 0 < N) { rowptr[base + 0] = off; off += c0; if (base + 0 == N - 1) rowptr[N] = off; }
    if (base + 1 < N) { rowptr[base + 1] = off; off += c1; if (base + 1 == N - 1) rowptr[N] = off; }
    if (base + 2 < N) { rowptr[base + 2] = off; off += c2; if (base + 2 == N - 1) rowptr[N] = off; }
    if (base + 3 < N) { rowptr[base + 3] = off; off += c3; if (base + 3 == N - 1) rowptr[N] = off; }
}

// bcursor[b] = rowptr[b*64]  (buckets are 64-node aligned)
__global__ void k_init_bcursor(const int* __restrict__ rowptr, int* __restrict__ bcursor,
                               int N, int NB) {
    int b = blockIdx.x * blockDim.x + threadIdx.x;
    if (b <= NB) bcursor[b] = rowptr[min(b * 64, N)];
}

// ---------------- tile-sorted bucket binning (coalesced writes) ----------------
// pairs[slot] = src | (dst&63)<<26, grouped by bucket (dst>>6).

__global__ void k_tile_bin(const int* __restrict__ src, const int* __restrict__ dst,
                           int* __restrict__ bcursor, unsigned int* __restrict__ pairs,
                           int E, int NB) {
    __shared__ unsigned int dbuf[BIN_T];
    __shared__ unsigned short perm[BIN_T];
    __shared__ int hist[NBMAX];
    __shared__ int lbase[NBMAX];
    __shared__ int gbase[NBMAX];
    __shared__ int tt[256];
    int t = threadIdx.x;
    int tilebase = blockIdx.x * BIN_T;
    int n = min(BIN_T, E - tilebase);
    for (int i = t; i < NB; i += 256) hist[i] = 0;
    __syncthreads();
    for (int i = t; i < n; i += 256) {
        unsigned int d = (unsigned int)dst[tilebase + i];
        dbuf[i] = d;
        atomicAdd(&hist[d >> 6], 1);
    }
    __syncthreads();
    // exclusive scan hist -> lbase
    {
        int b0 = t * 7, loc[7], run = 0;
        #pragma unroll
        for (int k = 0; k < 7; ++k) {
            int b = b0 + k;
            int c = (b < NB) ? hist[b] : 0;
            loc[k] = run; run += c;
        }
        tt[t] = run;
        __syncthreads();
        int val = run;
        for (int off = 1; off < 256; off <<= 1) {
            int add = (t >= off) ? tt[t - off] : 0;
            __syncthreads();
            tt[t] += add;
            __syncthreads();
        }
        int ebase = tt[t] - val;
        #pragma unroll
        for (int k = 0; k < 7; ++k) {
            int b = b0 + k;
            if (b < NB) lbase[b] = ebase + loc[k];
        }
    }
    __syncthreads();
    // claim global slots per bucket
    for (int i = t; i < NB; i += 256) {
        int c = hist[i];
        gbase[i] = (c > 0) ? atomicAdd(&bcursor[i], c) : 0;
    }
    __syncthreads();
    for (int i = t; i < NB; i += 256) hist[i] = lbase[i];
    __syncthreads();
    // scatter into bucket-sorted local order
    for (int i = t; i < n; i += 256) {
        int b = (int)(dbuf[i] >> 6);
        int p = atomicAdd(&hist[b], 1);
        perm[p] = (unsigned short)i;
    }
    __syncthreads();
    // coalesced output
    for (int p = t; p < n; p += 256) {
        int li = perm[p];
        unsigned int d = dbuf[li];
        int b = (int)(d >> 6);
        int addr = gbase[b] + (p - lbase[b]);
        pairs[addr] = (unsigned int)src[tilebase + li] | ((d & 63u) << 26);
    }
}

// per-bucket counting pass: pairs (bucket-grouped) -> csr_src (node-sorted),
// writes stay within the bucket's ~4KB span (L2-local).
__global__ void k_bucket_fill(const unsigned int* __restrict__ pairs,
                              const int* __restrict__ rowptr,
                              int* __restrict__ csr_src, int N) {
    __shared__ int cur[64];
    int b = blockIdx.x, t = threadIdx.x;
    int base = b * 64;
    if (t < 64) {
        int node = base + t;
        cur[t] = (node < N) ? rowptr[node] : 0;
    }
    __syncthreads();
    int lo = rowptr[base];
    int hi = rowptr[min(base + 64, N)];
    for (int e = lo + t; e < hi; e += 256) {
        unsigned int pk = pairs[e];
        int s = (int)(pk & 0x3FFFFFFu), dl = (int)(pk >> 26);
        int slot = atomicAdd(&cur[dl], 1);
        csr_src[slot] = s;
    }
}

// ---------------- layer-1 aggregation in 24-dim input space ----------------

__global__ void k_agg23(const int* __restrict__ rowptr, const int* __restrict__ csr_src,
                        const int* __restrict__ residue, const float* __restrict__ pos,
                        const float* __restrict__ dinv, const float* __restrict__ invd,
                        float* __restrict__ z0, int N) {
    __shared__ float accs[256 * 25];
    int t = threadIdx.x;
    int node = blockIdx.x * 256 + t;
    float* acc = accs + t * 25;
    #pragma unroll
    for (int k = 0; k < 24; ++k) acc[k] = 0.f;
    if (node < N) {
        int s0 = rowptr[node], s1 = rowptr[node + 1];
        for (int e = s0; e < s1; ++e) {
            int s = csr_src[e];
            float w = dinv[s];
            acc[residue[s]] += w;
            acc[20] += w * pos[s * 3 + 0];
            acc[21] += w * pos[s * 3 + 1];
            acc[22] += w * pos[s * 3 + 2];
        }
        float di = dinv[node], ii = invd[node];
        #pragma unroll
        for (int k = 0; k < 23; ++k) acc[k] *= di;
        acc[residue[node]] += ii;
        acc[20] += ii * pos[node * 3 + 0];
        acc[21] += ii * pos[node * 3 + 1];
        acc[22] += ii * pos[node * 3 + 2];
    }
    __syncthreads();
    int blockbase = blockIdx.x * 256;
    for (int q = t; q < 256 * 24; q += 256) {
        int row = q / 24, k = q - row * 24;
        int gn = blockbase + row;
        if (gn < N) z0[(size_t)gn * 24 + k] = accs[row * 25 + k];
    }
}

// x1 = relu(z0 @ W[23,128] + b), stored fp16
#define G24_ROWS 32
__global__ void k_gemm24(const float* __restrict__ z0, const float* __restrict__ W,
                         const float* __restrict__ b, __half* __restrict__ x1h, int N) {
    __shared__ float Ws[23 * 128];
    __shared__ float zr[G24_ROWS][25];
    int t = threadIdx.x;
    for (int q = t; q < 23 * 128; q += 256) Ws[q] = W[q];
    int blockbase = blockIdx.x * G24_ROWS;
    for (int q = t; q < G24_ROWS * 24; q += 256) {
        int row = q / 24, k = q - row * 24;
        int gn = blockbase + row;
        zr[row][k] = (gn < N) ? z0[(size_t)gn * 24 + k] : 0.f;
    }
    __syncthreads();
    int j = t & 127, slot = t >> 7;
    float bj = b[j];
    for (int r = slot; r < G24_ROWS; r += 2) {
        int gn = blockbase + r;
        if (gn >= N) break;
        float acc = bj;
        #pragma unroll
        for (int k = 0; k < 23; ++k) acc += zr[r][k] * Ws[k * 128 + j];
        x1h[(size_t)gn * HID + j] = __float2half(fmaxf(acc, 0.f));
    }
}

// ---------------- layer-2 aggregation: wave-per-node, fp16 gather ----------------

__global__ void k_agg128(const __half2* __restrict__ x1h, const int* __restrict__ rowptr,
                         const int* __restrict__ csr_src, const float* __restrict__ dinv,
                         const float* __restrict__ invd, float* __restrict__ z, int N) {
    int gw = (int)(((long long)blockIdx.x * blockDim.x + threadIdx.x) >> 6);
    int lane = threadIdx.x & 63;
    if (gw >= N) return;
    int s0 = rowptr[gw], s1 = rowptr[gw + 1];
    float ax = 0.f, ay = 0.f;
    int e = s0;
    for (; e + 4 <= s1; e += 4) {
        int sA = csr_src[e], sB = csr_src[e + 1], sC = csr_src[e + 2], sD = csr_src[e + 3];
        float wA = dinv[sA], wB = dinv[sB], wC = dinv[sC], wD = dinv[sD];
        float2 vA = __half22float2(x1h[(size_t)sA * 64 + lane]);
        float2 vB = __half22float2(x1h[(size_t)sB * 64 + lane]);
        float2 vC = __half22float2(x1h[(size_t)sC * 64 + lane]);
        float2 vD = __half22float2(x1h[(size_t)sD * 64 + lane]);
        ax += vA.x * wA; ay += vA.y * wA;
        ax += vB.x * wB; ay += vB.y * wB;
        ax += vC.x * wC; ay += vC.y * wC;
        ax += vD.x * wD; ay += vD.y * wD;
    }
    for (; e < s1; ++e) {
        int sA = csr_src[e];
        float wA = dinv[sA];
        float2 vA = __half22float2(x1h[(size_t)sA * 64 + lane]);
        ax += vA.x * wA; ay += vA.y * wA;
    }
    float di = dinv[gw], ii = invd[gw];
    float2 vs = __half22float2(x1h[(size_t)gw * 64 + lane]);
    float2 o; o.x = ax * di + vs.x * ii; o.y = ay * di + vs.y * ii;
    ((float2*)(z + (size_t)gw * HID))[lane] = o;
}

// ---------------- protein layer-2 gemm fused with mean-pool sum ----------------

__global__ void k_gemm_pool(const float* __restrict__ Z, const float* __restrict__ W,
                            const float* __restrict__ b, const int* __restrict__ batch,
                            float* __restrict__ psum, int N) {
    __shared__ float red[8][128];
    int tile = blockIdx.x * 32;
    int cg = threadIdx.x & 31, rg = threadIdx.x >> 5;
    int j0 = cg * 4;
    int r[4]; bool val[4];
    #pragma unroll
    for (int m = 0; m < 4; ++m) {
        int rr = tile + rg * 4 + m;
        val[m] = rr < N;
        r[m] = val[m] ? rr : (N - 1);
    }
    float acc[4][4] = {};
    for (int k4 = 0; k4 < 32; ++k4) {
        int k = k4 * 4;
        float4 w0 = *(const float4*)&W[(k + 0) * HID + j0];
        float4 w1 = *(const float4*)&W[(k + 1) * HID + j0];
        float4 w2 = *(const float4*)&W[(k + 2) * HID + j0];
        float4 w3 = *(const float4*)&W[(k + 3) * HID + j0];
        #pragma unroll
        for (int m = 0; m < 4; ++m) {
            float4 x = *(const float4*)&Z[(size_t)r[m] * HID + k];
            acc[m][0] += x.x * w0.x + x.y * w1.x + x.z * w2.x + x.w * w3.x;
            acc[m][1] += x.x * w0.y + x.y * w1.y + x.z * w2.y + x.w * w3.y;
            acc[m][2] += x.x * w0.z + x.y * w1.z + x.z * w2.z + x.w * w3.z;
            acc[m][3] += x.x * w0.w + x.y * w1.w + x.z * w2.w + x.w * w3.w;
        }
    }
    float4 bb = *(const float4*)&b[j0];
    float bbv[4] = {bb.x, bb.y, bb.z, bb.w};
    float v[4][4];
    #pragma unroll
    for (int m = 0; m < 4; ++m)
        #pragma unroll
        for (int c = 0; c < 4; ++c)
            v[m][c] = fmaxf(acc[m][c] + bbv[c], 0.f);

    int gfirst = batch[tile];
    int glast = batch[min(tile + 31, N - 1)];
    if (gfirst == glast) {
        float s0 = 0.f, s1 = 0.f, s2 = 0.f, s3 = 0.f;
        #pragma unroll
        for (int m = 0; m < 4; ++m) if (val[m]) {
            s0 += v[m][0]; s1 += v[m][1]; s2 += v[m][2]; s3 += v[m][3];
        }
        *(float4*)&red[rg][j0] = make_float4(s0, s1, s2, s3);
        __syncthreads();
        if (threadIdx.x < 128) {
            float tot = 0.f;
            #pragma unroll
            for (int q = 0; q < 8; ++q) tot += red[q][threadIdx.x];
            atomicAdd(&psum[gfirst * HID + threadIdx.x], tot);
        }
    } else {
        #pragma unroll
        for (int m = 0; m < 4; ++m) if (val[m]) {
            int g = batch[r[m]];
            #pragma unroll
            for (int c = 0; c < 4; ++c)
                atomicAdd(&psum[g * HID + j0 + c], v[m][c]);
        }
    }
}

__global__ void k_count_batch(const int* __restrict__ batch, int* __restrict__ pcnt, int N) {
    __shared__ int h[64];
    if (threadIdx.x < 64) h[threadIdx.x] = 0;
    __syncthreads();
    for (int i = blockIdx.x * blockDim.x + threadIdx.x; i < N; i += gridDim.x * blockDim.x)
        atomicAdd(&h[batch[i]], 1);
    __syncthreads();
    if (threadIdx.x < 64 && h[threadIdx.x] > 0)
        atomicAdd(&pcnt[threadIdx.x], h[threadIdx.x]);
}

// ctxW[g] = (psum[g]/cnt[g]) @ W1[128:,:] + b1
__global__ void k_ctxw_div(const float* __restrict__ psum, const int* __restrict__ pcnt,
                           const float* __restrict__ W1, const float* __restrict__ b1,
                           float* __restrict__ ctxW) {
    __shared__ float pr[128];
    int g = blockIdx.x, j = threadIdx.x;
    pr[j] = psum[g * HID + j] / fmaxf((float)pcnt[g], 1.f);
    __syncthreads();
    float a = b1[j];
    #pragma unroll 4
    for (int k = 0; k < HID; ++k) a += pr[k] * W1[(HID + k) * HID + j];
    ctxW[g * HID + j] = a;
}

// ---------------- mm layer-2 gemm fused with head ----------------

__global__ void k_mm_tail(const float* __restrict__ Z, const float* __restrict__ Wm2,
                          const float* __restrict__ bm2, const int* __restrict__ batch,
                          const float* __restrict__ ctxW, const float* __restrict__ W1,
                          const float* __restrict__ W2, const float* __restrict__ b2,
                          float* __restrict__ out, int N) {
    __shared__ float Xs[32][132];
    __shared__ float Hs[32][132];
    int tile = blockIdx.x * 32;
    int cg = threadIdx.x & 31, rg = threadIdx.x >> 5;
    int j0 = cg * 4;
    int r[4]; bool val[4];
    #pragma unroll
    for (int m = 0; m < 4; ++m) {
        int rr = tile + rg * 4 + m;
        val[m] = rr < N;
        r[m] = val[m] ? rr : (N - 1);
    }
    // phase 1: x2 tile
    {
        float acc[4][4] = {};
        for (int k4 = 0; k4 < 32; ++k4) {
            int k = k4 * 4;
            float4 w0 = *(const float4*)&Wm2[(k + 0) * HID + j0];
            float4 w1 = *(const float4*)&Wm2[(k + 1) * HID + j0];
            float4 w2 = *(const float4*)&Wm2[(k + 2) * HID + j0];
            float4 w3 = *(const float4*)&Wm2[(k + 3) * HID + j0];
            #pragma unroll
            for (int m = 0; m < 4; ++m) {
                float4 x = *(const float4*)&Z[(size_t)r[m] * HID + k];
                acc[m][0] += x.x * w0.x + x.y * w1.x + x.z * w2.x + x.w * w3.x;
                acc[m][1] += x.x * w0.y + x.y * w1.y + x.z * w2.y + x.w * w3.y;
                acc[m][2] += x.x * w0.z + x.y * w1.z + x.z * w2.z + x.w * w3.z;
                acc[m][3] += x.x * w0.w + x.y * w1.w + x.z * w2.w + x.w * w3.w;
            }
        }
        float4 bb = *(const float4*)&bm2[j0];
        float bbv[4] = {bb.x, bb.y, bb.z, bb.w};
        #pragma unroll
        for (int m = 0; m < 4; ++m) {
            int row = rg * 4 + m;
            *(float4*)&Xs[row][j0] = make_float4(
                fmaxf(acc[m][0] + bbv[0], 0.f), fmaxf(acc[m][1] + bbv[1], 0.f),
                fmaxf(acc[m][2] + bbv[2], 0.f), fmaxf(acc[m][3] + bbv[3], 0.f));
        }
    }
    __syncthreads();
    // phase 2: h tile
    {
        float acc[4][4] = {};
        for (int k4 = 0; k4 < 32; ++k4) {
            int k = k4 * 4;
            float4 w0 = *(const float4*)&W1[(k + 0) * HID + j0];
            float4 w1 = *(const float4*)&W1[(k + 1) * HID + j0];
            float4 w2 = *(const float4*)&W1[(k + 2) * HID + j0];
            float4 w3 = *(const float4*)&W1[(k + 3) * HID + j0];
            #pragma unroll
            for (int m = 0; m < 4; ++m) {
                float4 x = *(const float4*)&Xs[rg * 4 + m][k];
                acc[m][0] += x.x * w0.x + x.y * w1.x + x.z * w2.x + x.w * w3.x;
                acc[m][1] += x.x * w0.y + x.y * w1.y + x.z * w2.y + x.w * w3.y;
                acc[m][2] += x.x * w0.z + x.y * w1.z + x.z * w2.z + x.w * w3.z;
                acc[m][3] += x.x * w0.w + x.y * w1.w + x.z * w2.w + x.w * w3.w;
            }
        }
        #pragma unroll
        for (int m = 0; m < 4; ++m) {
            int g = batch[r[m]];
            float4 cx = *(const float4*)&ctxW[g * HID + j0];
            float cxv[4] = {cx.x, cx.y, cx.z, cx.w};
            int row = rg * 4 + m;
            *(float4*)&Hs[row][j0] = make_float4(
                fmaxf(acc[m][0] + cxv[0], 0.f), fmaxf(acc[m][1] + cxv[1], 0.f),
                fmaxf(acc[m][2] + cxv[2], 0.f), fmaxf(acc[m][3] + cxv[3], 0.f));
        }
    }
    __syncthreads();
    // phase 3: out = h @ W2 + b2
    {
        int row = threadIdx.x >> 3, seg = threadIdx.x & 7;
        float p0 = 0.f, p1 = 0.f, p2 = 0.f;
        #pragma unroll
        for (int kk = 0; kk < 16; ++kk) {
            int k = seg * 16 + kk;
            float hv = Hs[row][k];
            p0 += hv * W2[k * 3 + 0];
            p1 += hv * W2[k * 3 + 1];
            p2 += hv * W2[k * 3 + 2];
        }
        __syncthreads();
        Xs[row][seg * 3 + 0] = p0;
        Xs[row][seg * 3 + 1] = p1;
        Xs[row][seg * 3 + 2] = p2;
        __syncthreads();
        if (threadIdx.x < 96) {
            int rw = threadIdx.x / 3, c = threadIdx.x - rw * 3;
            int gr = tile + rw;
            if (gr < N) {
                float a = b2[c];
                #pragma unroll
                for (int q = 0; q < 8; ++q) a += Xs[rw][q * 3 + c];
                out[(size_t)gr * 3 + c] = a;
            }
        }
    }
}

// ---------------- launch ----------------

extern "C" void kernel_launch(void* const* d_in, const int* in_sizes, int n_in,
                              void* d_out, int out_size, void* d_ws, size_t ws_size,
                              hipStream_t stream) {
    const int*   residue_p = (const int*)d_in[0];
    const float* pos_p     = (const float*)d_in[1];
    const int*   ei_p      = (const int*)d_in[2];
    const int*   batch_p   = (const int*)d_in[3];
    const int*   residue_m = (const int*)d_in[4];
    const float* pos_m     = (const float*)d_in[5];
    const int*   ei_m      = (const int*)d_in[6];
    const int*   batch_m   = (const int*)d_in[7];
    const float* W_p1 = (const float*)d_in[8];
    const float* b_p1 = (const float*)d_in[9];
    const float* W_p2 = (const float*)d_in[10];
    const float* b_p2 = (const float*)d_in[11];
    const float* W_m1 = (const float*)d_in[12];
    const float* b_m1 = (const float*)d_in[13];
    const float* W_m2 = (const float*)d_in[14];
    const float* b_m2 = (const float*)d_in[15];
    const float* W1   = (const float*)d_in[16];
    const float* b1   = (const float*)d_in[17];
    const float* W2   = (const float*)d_in[18];
    const float* b2   = (const float*)d_in[19];

    const int N_P = in_sizes[0];
    const int E_P = in_sizes[2] / 2;
    const int N_M = in_sizes[4];
    const int E_M = in_sizes[6] / 2;
    const int G = 64;

    char* ws = (char*)d_ws;
    size_t off = 0;
    auto alloc = [&](size_t bytes) {
        char* p = ws + off;
        off += (bytes + 511) & ~size_t(511);
        return p;
    };
    float*        bufA    = (float*)alloc((size_t)N_P * HID * 4);   // z (fp32)
    float*        bufB    = (float*)alloc((size_t)N_P * 24 * 4);    // z0
    __half*       x1h     = (__half*)alloc((size_t)N_P * HID * 2);  // x1 fp16
    int*          deg     = (int*)  alloc((size_t)N_P * 4);
    float*        dinv    = (float*)alloc((size_t)N_P * 4);
    float*        invd    = (float*)alloc((size_t)N_P * 4);
    int*          rowptr  = (int*)  alloc((size_t)(N_P + 1) * 4);
    int*          partials= (int*)  alloc(256 * 4);
    int*          bcursor = (int*)  alloc((NBMAX + 1) * 4);
    unsigned int* pairs   = (unsigned int*)alloc((size_t)E_P * 4);
    int*          csr_src = (int*)  alloc((size_t)E_P * 4);
    float*        psum    = (float*)alloc((size_t)G * HID * 4);
    int*          pcnt    = (int*)  alloc((size_t)G * 4);
    float*        ctxW    = (float*)alloc((size_t)G * HID * 4);

    auto run_branch = [&](const int* residue, const float* pos, const int* ei,
                          const float* Wl1, const float* bl1, int N, int E) {
        const int* srcp = ei;
        const int* dstp = ei + E;
        int NB = (N + 63) / 64;
        int nbp = (N + SCAN_BS - 1) / SCAN_BS;

        hipMemsetAsync(deg, 0, (size_t)N * 4, stream);
        k_count_deg<<<(E + 255) / 256, 256, 0, stream>>>(dstp, deg, E);
        k_deg_finalize<<<(N + 255) / 256, 256, 0, stream>>>(deg, dinv, invd, N);
        k_scan_partial<<<nbp, SCAN_TPB, 0, stream>>>(deg, partials, N);
        k_scan_root<<<1, SCAN_TPB, 0, stream>>>(partials, nbp);
        k_scan_final<<<nbp, SCAN_TPB, 0, stream>>>(deg, partials, rowptr, N);
        k_init_bcursor<<<(NB + 256) / 256, 256, 0, stream>>>(rowptr, bcursor, N, NB);
        k_tile_bin<<<(E + BIN_T - 1) / BIN_T, 256, 0, stream>>>(srcp, dstp, bcursor, pairs, E, NB);
        k_bucket_fill<<<NB, 256, 0, stream>>>(pairs, rowptr, csr_src, N);

        k_agg23<<<(N + 255) / 256, 256, 0, stream>>>(rowptr, csr_src, residue, pos,
                                                     dinv, invd, bufB, N);
        k_gemm24<<<(N + G24_ROWS - 1) / G24_ROWS, 256, 0, stream>>>(bufB, Wl1, bl1, x1h, N);
        k_agg128<<<(N + 3) / 4, 256, 0, stream>>>((const __half2*)x1h, rowptr, csr_src,
                                                  dinv, invd, bufA, N);
        // result: bufA (z, fp32)
    };

    // ---- protein branch ----
    run_branch(residue_p, pos_p, ei_p, W_p1, b_p1, N_P, E_P);
    hipMemsetAsync(psum, 0, (size_t)G * HID * 4, stream);
    hipMemsetAsync(pcnt, 0, (size_t)G * 4, stream);
    k_gemm_pool<<<(N_P + 31) / 32, 256, 0, stream>>>(bufA, W_p2, b_p2, batch_p, psum, N_P);
    k_count_batch<<<256, 256, 0, stream>>>(batch_p, pcnt, N_P);
    k_ctxw_div<<<G, HID, 0, stream>>>(psum, pcnt, W1, b1, ctxW);

    // ---- micromolecule branch ----
    run_branch(residue_m, pos_m, ei_m, W_m1, b_m1, N_M, E_M);
    k_mm_tail<<<(N_M + 31) / 32, 256, 0, stream>>>(bufA, W_m2, b_m2, batch_m, ctxW,
                                                   W1, W2, b2, (float*)d_out, N_M);
}

// Round 6
// 537.641 us; speedup vs baseline: 4.4499x; 1.1990x over previous
//
#include <hip/hip_runtime.h>
#include <hip/hip_bf16.h>
#include <hip/hip_fp16.h>

#define HID 128
#define BIN_T 8192
#define NBMAX 1664   // max 64-node buckets (N <= 106496)

typedef _Float16 f16;
typedef __attribute__((ext_vector_type(8))) _Float16 f16x8;
typedef __attribute__((ext_vector_type(4))) float f32x4;

// ---------------- degree ----------------

__global__ void k_count_deg(const int* __restrict__ dst, int* __restrict__ deg, int E) {
    int e = blockIdx.x * blockDim.x + threadIdx.x;
    if (e < E) atomicAdd(&deg[dst[e]], 1);
}

__global__ void k_deg_finalize(const int* __restrict__ deg, float* __restrict__ dinv,
                               float* __restrict__ invd, int N) {
    int i = blockIdx.x * blockDim.x + threadIdx.x;
    if (i < N) {
        float d = (float)deg[i] + 1.0f;   // +1 self loop
        dinv[i] = 1.0f / sqrtf(d);
        invd[i] = 1.0f / d;
    }
}

// ---------------- exclusive scan (deg -> rowptr) ----------------

#define SCAN_TPB 256
#define SCAN_VPT 4
#define SCAN_BS (SCAN_TPB * SCAN_VPT)

__global__ void k_scan_partial(const int* __restrict__ deg, int* __restrict__ partials, int N) {
    __shared__ int lds[SCAN_TPB];
    int base = blockIdx.x * SCAN_BS + threadIdx.x * SCAN_VPT;
    int s = 0;
    #pragma unroll
    for (int c = 0; c < SCAN_VPT; ++c) { int idx = base + c; if (idx < N) s += deg[idx]; }
    lds[threadIdx.x] = s;
    __syncthreads();
    for (int off = SCAN_TPB / 2; off > 0; off >>= 1) {
        if (threadIdx.x < off) lds[threadIdx.x] += lds[threadIdx.x + off];
        __syncthreads();
    }
    if (threadIdx.x == 0) partials[blockIdx.x] = lds[0];
}

__global__ void k_scan_root(int* __restrict__ partials, int nb) {
    __shared__ int lds[SCAN_TPB];
    int t = threadIdx.x;
    int v = (t < nb) ? partials[t] : 0;
    lds[t] = v;
    __syncthreads();
    for (int off = 1; off < SCAN_TPB; off <<= 1) {
        int add = (t >= off) ? lds[t - off] : 0;
        __syncthreads();
        lds[t] += add;
        __syncthreads();
    }
    if (t < nb) partials[t] = lds[t] - v;   // exclusive
}

__global__ void k_scan_final(const int* __restrict__ deg, const int* __restrict__ partials,
                             int* __restrict__ rowptr, int N) {
    __shared__ int lds[SCAN_TPB];
    int base = blockIdx.x * SCAN_BS + threadIdx.x * SCAN_VPT;
    int c0 = 0, c1 = 0, c2 = 0, c3 = 0;
    if (base + 0 < N) c0 = deg[base + 0];
    if (base + 1 < N) c1 = deg[base + 1];
    if (base + 2 < N) c2 = deg[base + 2];
    if (base + 3 < N) c3 = deg[base + 3];
    int s = c0 + c1 + c2 + c3;
    lds[threadIdx.x] = s;
    __syncthreads();
    for (int off = 1; off < SCAN_TPB; off <<= 1) {
        int add = (threadIdx.x >= off) ? lds[threadIdx.x - off] : 0;
        __syncthreads();
        lds[threadIdx.x] += add;
        __syncthreads();
    }
    int off = lds[threadIdx.x] - s + partials[blockIdx.x];
    if (base + 0 < N) { rowptr[base + 0] = off; off += c0; if (base + 0 == N - 1) rowptr[N] = off; }
    if (base + 1 < N) { rowptr[base + 1] = off; off += c1; if (base + 1 == N - 1) rowptr[N] = off; }
    if (base + 2 < N) { rowptr[base + 2] = off; off += c2; if (base + 2 == N - 1) rowptr[N] = off; }
    if (base + 3 < N) { rowptr[base + 3] = off; off += c3; if (base + 3 == N - 1) rowptr[N] = off; }
}

// bcursor[b] = rowptr[b*64]  (buckets are 64-node aligned)
__global__ void k_init_bcursor(const int* __restrict__ rowptr, int* __restrict__ bcursor,
                               int N, int NB) {
    int b = blockIdx.x * blockDim.x + threadIdx.x;
    if (b <= NB) bcursor[b] = rowptr[min(b * 64, N)];
}

// ---------------- tile-sorted bucket binning (coalesced writes) ----------------
// pairs[slot] = src | (dst&63)<<26, grouped by bucket (dst>>6).

__global__ void k_tile_bin(const int* __restrict__ src, const int* __restrict__ dst,
                           int* __restrict__ bcursor, unsigned int* __restrict__ pairs,
                           int E, int NB) {
    __shared__ unsigned int dbuf[BIN_T];
    __shared__ unsigned short perm[BIN_T];
    __shared__ int hist[NBMAX];
    __shared__ int lbase[NBMAX];
    __shared__ int gbase[NBMAX];
    __shared__ int tt[256];
    int t = threadIdx.x;
    int tilebase = blockIdx.x * BIN_T;
    int n = min(BIN_T, E - tilebase);
    for (int i = t; i < NB; i += 256) hist[i] = 0;
    __syncthreads();
    for (int i = t; i < n; i += 256) {
        unsigned int d = (unsigned int)dst[tilebase + i];
        dbuf[i] = d;
        atomicAdd(&hist[d >> 6], 1);
    }
    __syncthreads();
    // exclusive scan hist -> lbase
    {
        int b0 = t * 7, loc[7], run = 0;
        #pragma unroll
        for (int k = 0; k < 7; ++k) {
            int b = b0 + k;
            int c = (b < NB) ? hist[b] : 0;
            loc[k] = run; run += c;
        }
        tt[t] = run;
        __syncthreads();
        int val = run;
        for (int off = 1; off < 256; off <<= 1) {
            int add = (t >= off) ? tt[t - off] : 0;
            __syncthreads();
            tt[t] += add;
            __syncthreads();
        }
        int ebase = tt[t] - val;
        #pragma unroll
        for (int k = 0; k < 7; ++k) {
            int b = b0 + k;
            if (b < NB) lbase[b] = ebase + loc[k];
        }
    }
    __syncthreads();
    // claim global slots per bucket
    for (int i = t; i < NB; i += 256) {
        int c = hist[i];
        gbase[i] = (c > 0) ? atomicAdd(&bcursor[i], c) : 0;
    }
    __syncthreads();
    for (int i = t; i < NB; i += 256) hist[i] = lbase[i];
    __syncthreads();
    // scatter into bucket-sorted local order
    for (int i = t; i < n; i += 256) {
        int b = (int)(dbuf[i] >> 6);
        int p = atomicAdd(&hist[b], 1);
        perm[p] = (unsigned short)i;
    }
    __syncthreads();
    // coalesced output
    for (int p = t; p < n; p += 256) {
        int li = perm[p];
        unsigned int d = dbuf[li];
        int b = (int)(d >> 6);
        int addr = gbase[b] + (p - lbase[b]);
        pairs[addr] = (unsigned int)src[tilebase + li] | ((d & 63u) << 26);
    }
}

// per-bucket counting pass: pairs (bucket-grouped) -> csr_src (node-sorted)
__global__ void k_bucket_fill(const unsigned int* __restrict__ pairs,
                              const int* __restrict__ rowptr,
                              int* __restrict__ csr_src, int N) {
    __shared__ int cur[64];
    int b = blockIdx.x, t = threadIdx.x;
    int base = b * 64;
    if (t < 64) {
        int node = base + t;
        cur[t] = (node < N) ? rowptr[node] : 0;
    }
    __syncthreads();
    int lo = rowptr[base];
    int hi = rowptr[min(base + 64, N)];
    for (int e = lo + t; e < hi; e += 256) {
        unsigned int pk = pairs[e];
        int s = (int)(pk & 0x3FFFFFFu), dl = (int)(pk >> 26);
        int slot = atomicAdd(&cur[dl], 1);
        csr_src[slot] = s;
    }
}

// ---------------- layer-1 aggregation in 24-dim input space ----------------

__global__ void k_agg23(const int* __restrict__ rowptr, const int* __restrict__ csr_src,
                        const int* __restrict__ residue, const float* __restrict__ pos,
                        const float* __restrict__ dinv, const float* __restrict__ invd,
                        float* __restrict__ z0, int N) {
    __shared__ float accs[256 * 25];
    int t = threadIdx.x;
    int node = blockIdx.x * 256 + t;
    float* acc = accs + t * 25;
    #pragma unroll
    for (int k = 0; k < 24; ++k) acc[k] = 0.f;
    if (node < N) {
        int s0 = rowptr[node], s1 = rowptr[node + 1];
        for (int e = s0; e < s1; ++e) {
            int s = csr_src[e];
            float w = dinv[s];
            acc[residue[s]] += w;
            acc[20] += w * pos[s * 3 + 0];
            acc[21] += w * pos[s * 3 + 1];
            acc[22] += w * pos[s * 3 + 2];
        }
        float di = dinv[node], ii = invd[node];
        #pragma unroll
        for (int k = 0; k < 23; ++k) acc[k] *= di;
        acc[residue[node]] += ii;
        acc[20] += ii * pos[node * 3 + 0];
        acc[21] += ii * pos[node * 3 + 1];
        acc[22] += ii * pos[node * 3 + 2];
    }
    __syncthreads();
    int blockbase = blockIdx.x * 256;
    for (int q = t; q < 256 * 24; q += 256) {
        int row = q / 24, k = q - row * 24;
        int gn = blockbase + row;
        if (gn < N) z0[(size_t)gn * 24 + k] = accs[row * 25 + k];
    }
}

// x1 = relu(z0 @ W[23,128] + b), stored fp16
#define G24_ROWS 32
__global__ void k_gemm24(const float* __restrict__ z0, const float* __restrict__ W,
                         const float* __restrict__ b, __half* __restrict__ x1h, int N) {
    __shared__ float Ws[23 * 128];
    __shared__ float zr[G24_ROWS][25];
    int t = threadIdx.x;
    for (int q = t; q < 23 * 128; q += 256) Ws[q] = W[q];
    int blockbase = blockIdx.x * G24_ROWS;
    for (int q = t; q < G24_ROWS * 24; q += 256) {
        int row = q / 24, k = q - row * 24;
        int gn = blockbase + row;
        zr[row][k] = (gn < N) ? z0[(size_t)gn * 24 + k] : 0.f;
    }
    __syncthreads();
    int j = t & 127, slot = t >> 7;
    float bj = b[j];
    for (int r = slot; r < G24_ROWS; r += 2) {
        int gn = blockbase + r;
        if (gn >= N) break;
        float acc = bj;
        #pragma unroll
        for (int k = 0; k < 23; ++k) acc += zr[r][k] * Ws[k * 128 + j];
        x1h[(size_t)gn * HID + j] = __float2half(fmaxf(acc, 0.f));
    }
}

// ---------------- layer-2 aggregation: wave-per-node, fp16 gather ----------------

__global__ void k_agg128(const __half2* __restrict__ x1h, const int* __restrict__ rowptr,
                         const int* __restrict__ csr_src, const float* __restrict__ dinv,
                         const float* __restrict__ invd, float* __restrict__ z, int N) {
    int gw = (int)(((long long)blockIdx.x * blockDim.x + threadIdx.x) >> 6);
    int lane = threadIdx.x & 63;
    if (gw >= N) return;
    int s0 = rowptr[gw], s1 = rowptr[gw + 1];
    float ax = 0.f, ay = 0.f;
    int e = s0;
    for (; e + 4 <= s1; e += 4) {
        int sA = csr_src[e], sB = csr_src[e + 1], sC = csr_src[e + 2], sD = csr_src[e + 3];
        float wA = dinv[sA], wB = dinv[sB], wC = dinv[sC], wD = dinv[sD];
        float2 vA = __half22float2(x1h[(size_t)sA * 64 + lane]);
        float2 vB = __half22float2(x1h[(size_t)sB * 64 + lane]);
        float2 vC = __half22float2(x1h[(size_t)sC * 64 + lane]);
        float2 vD = __half22float2(x1h[(size_t)sD * 64 + lane]);
        ax += vA.x * wA; ay += vA.y * wA;
        ax += vB.x * wB; ay += vB.y * wB;
        ax += vC.x * wC; ay += vC.y * wC;
        ax += vD.x * wD; ay += vD.y * wD;
    }
    for (; e < s1; ++e) {
        int sA = csr_src[e];
        float wA = dinv[sA];
        float2 vA = __half22float2(x1h[(size_t)sA * 64 + lane]);
        ax += vA.x * wA; ay += vA.y * wA;
    }
    float di = dinv[gw], ii = invd[gw];
    float2 vs = __half22float2(x1h[(size_t)gw * 64 + lane]);
    float2 o; o.x = ax * di + vs.x * ii; o.y = ay * di + vs.y * ii;
    ((float2*)(z + (size_t)gw * HID))[lane] = o;
}

// ---------------- weight prep: fp16 transposed tables ----------------
// T[n][k] = W[k][n]

__global__ void k_prep_w(const float* __restrict__ Wp2, const float* __restrict__ Wm2,
                         const float* __restrict__ W1,
                         f16* __restrict__ Wp2t, f16* __restrict__ Wm2t,
                         f16* __restrict__ W1at) {
    int idx = blockIdx.x * 256 + threadIdx.x;
    if (idx >= 128 * 128) return;
    int n = idx & 127, k = idx >> 7;
    Wp2t[n * 128 + k] = (f16)Wp2[k * 128 + n];
    Wm2t[n * 128 + k] = (f16)Wm2[k * 128 + n];
    W1at[n * 128 + k] = (f16)W1[k * 128 + n];
}

// ---------------- MFMA GEMM + fused mean-pool (protein x2) ----------------
// x2 = relu(Z @ W + b); psum[g] += x2 rows. 64 rows/block, 4 waves.
// frag layouts (16x16x32 f16): A lane: row=l&15, k=(l>>4)*8+e; B lane: col=l&15, k=(l>>4)*8+e
// C lane: col=l&15, row=(l>>4)*4+reg.

__global__ __launch_bounds__(256) void k_gemm_pool_mfma(
        const float* __restrict__ Z, const f16* __restrict__ Wt,
        const float* __restrict__ b, const int* __restrict__ batch,
        float* __restrict__ psum, int N) {
    __shared__ float x2s[64][132];
    __shared__ int bsh[64];
    int tile = blockIdx.x * 64;
    int t = threadIdx.x, lane = t & 63, w = t >> 6;
    int lr = lane & 15, kb = lane >> 4;
    int zrow = min(tile + w * 16 + lr, N - 1);
    f16x8 afr[4];
    #pragma unroll
    for (int kc = 0; kc < 4; ++kc) {
        const float* p = Z + (size_t)zrow * HID + kc * 32 + kb * 8;
        float4 v0 = *(const float4*)p;
        float4 v1 = *(const float4*)(p + 4);
        f16x8 a;
        a[0] = (f16)v0.x; a[1] = (f16)v0.y; a[2] = (f16)v0.z; a[3] = (f16)v0.w;
        a[4] = (f16)v1.x; a[5] = (f16)v1.y; a[6] = (f16)v1.z; a[7] = (f16)v1.w;
        afr[kc] = a;
    }
    #pragma unroll
    for (int ct = 0; ct < 8; ++ct) {
        f32x4 acc = {0.f, 0.f, 0.f, 0.f};
        int col = ct * 16 + lr;
        const f16* wp = Wt + (size_t)col * HID + kb * 8;
        #pragma unroll
        for (int kc = 0; kc < 4; ++kc) {
            f16x8 bf = *(const f16x8*)(wp + kc * 32);
            acc = __builtin_amdgcn_mfma_f32_16x16x32_f16(afr[kc], bf, acc, 0, 0, 0);
        }
        float bj = b[col];
        #pragma unroll
        for (int r = 0; r < 4; ++r) {
            int lrow = w * 16 + kb * 4 + r;
            x2s[lrow][col] = fmaxf(acc[r] + bj, 0.f);
        }
    }
    if (t < 64) bsh[t] = batch[min(tile + t, N - 1)];
    __syncthreads();
    int rows = min(64, N - tile);
    if (t < 128) {
        if (bsh[0] == bsh[rows - 1]) {
            float s = 0.f;
            for (int r = 0; r < rows; ++r) s += x2s[r][t];
            atomicAdd(&psum[bsh[0] * HID + t], s);
        } else {
            int cg = bsh[0]; float s = 0.f;
            for (int r = 0; r < rows; ++r) {
                int g = bsh[r];
                if (g != cg) { atomicAdd(&psum[cg * HID + t], s); s = 0.f; cg = g; }
                s += x2s[r][t];
            }
            atomicAdd(&psum[cg * HID + t], s);
        }
    }
}

__global__ void k_count_batch(const int* __restrict__ batch, int* __restrict__ pcnt, int N) {
    __shared__ int h[64];
    if (threadIdx.x < 64) h[threadIdx.x] = 0;
    __syncthreads();
    for (int i = blockIdx.x * blockDim.x + threadIdx.x; i < N; i += gridDim.x * blockDim.x)
        atomicAdd(&h[batch[i]], 1);
    __syncthreads();
    if (threadIdx.x < 64 && h[threadIdx.x] > 0)
        atomicAdd(&pcnt[threadIdx.x], h[threadIdx.x]);
}

// ctxW[g] = (psum[g]/cnt[g]) @ W1[128:,:] + b1
__global__ void k_ctxw_div(const float* __restrict__ psum, const int* __restrict__ pcnt,
                           const float* __restrict__ W1, const float* __restrict__ b1,
                           float* __restrict__ ctxW) {
    __shared__ float pr[128];
    int g = blockIdx.x, j = threadIdx.x;
    pr[j] = psum[g * HID + j] / fmaxf((float)pcnt[g], 1.f);
    __syncthreads();
    float a = b1[j];
    #pragma unroll 4
    for (int k = 0; k < HID; ++k) a += pr[k] * W1[(HID + k) * HID + j];
    ctxW[g * HID + j] = a;
}

// ---------------- MFMA mm tail: x2 -> h -> out, fused ----------------

__global__ __launch_bounds__(256) void k_mm_tail_mfma(
        const float* __restrict__ Z, const f16* __restrict__ Wm2t,
        const float* __restrict__ bm2, const int* __restrict__ batch,
        const float* __restrict__ ctxW, const f16* __restrict__ W1at,
        const float* __restrict__ W2, const float* __restrict__ b2,
        float* __restrict__ out, int N) {
    __shared__ f16 x2s[64][136];
    __shared__ f16 hs[64][136];
    __shared__ float part[64][4][3];
    int tile = blockIdx.x * 64;
    int t = threadIdx.x, lane = t & 63, w = t >> 6;
    int lr = lane & 15, kb = lane >> 4;
    // phase 1: x2 = relu(Z @ Wm2 + bm2) -> LDS fp16
    {
        int zrow = min(tile + w * 16 + lr, N - 1);
        f16x8 afr[4];
        #pragma unroll
        for (int kc = 0; kc < 4; ++kc) {
            const float* p = Z + (size_t)zrow * HID + kc * 32 + kb * 8;
            float4 v0 = *(const float4*)p;
            float4 v1 = *(const float4*)(p + 4);
            f16x8 a;
            a[0] = (f16)v0.x; a[1] = (f16)v0.y; a[2] = (f16)v0.z; a[3] = (f16)v0.w;
            a[4] = (f16)v1.x; a[5] = (f16)v1.y; a[6] = (f16)v1.z; a[7] = (f16)v1.w;
            afr[kc] = a;
        }
        #pragma unroll
        for (int ct = 0; ct < 8; ++ct) {
            f32x4 acc = {0.f, 0.f, 0.f, 0.f};
            int col = ct * 16 + lr;
            const f16* wp = Wm2t + (size_t)col * HID + kb * 8;
            #pragma unroll
            for (int kc = 0; kc < 4; ++kc) {
                f16x8 bf = *(const f16x8*)(wp + kc * 32);
                acc = __builtin_amdgcn_mfma_f32_16x16x32_f16(afr[kc], bf, acc, 0, 0, 0);
            }
            float bj = bm2[col];
            #pragma unroll
            for (int r = 0; r < 4; ++r)
                x2s[w * 16 + kb * 4 + r][col] = (f16)fmaxf(acc[r] + bj, 0.f);
        }
    }
    __syncthreads();
    // phase 2: h = relu(x2 @ W1a + ctxW[batch]) -> LDS fp16
    {
        f16x8 afr[4];
        #pragma unroll
        for (int kc = 0; kc < 4; ++kc)
            afr[kc] = *(const f16x8*)&x2s[w * 16 + lr][kc * 32 + kb * 8];
        int gidx[4];
        #pragma unroll
        for (int r = 0; r < 4; ++r)
            gidx[r] = batch[min(tile + w * 16 + kb * 4 + r, N - 1)];
        #pragma unroll
        for (int ct = 0; ct < 8; ++ct) {
            f32x4 acc = {0.f, 0.f, 0.f, 0.f};
            int col = ct * 16 + lr;
            const f16* wp = W1at + (size_t)col * HID + kb * 8;
            #pragma unroll
            for (int kc = 0; kc < 4; ++kc) {
                f16x8 bf = *(const f16x8*)(wp + kc * 32);
                acc = __builtin_amdgcn_mfma_f32_16x16x32_f16(afr[kc], bf, acc, 0, 0, 0);
            }
            #pragma unroll
            for (int r = 0; r < 4; ++r) {
                float cx = ctxW[gidx[r] * HID + col];
                hs[w * 16 + kb * 4 + r][col] = (f16)fmaxf(acc[r] + cx, 0.f);
            }
        }
    }
    __syncthreads();
    // phase 3: out = h @ W2 + b2 (128->3), 4 k-segments of 32 per row
    {
        int row = t >> 2, seg = t & 3;
        float p0 = 0.f, p1 = 0.f, p2 = 0.f;
        #pragma unroll
        for (int kk = 0; kk < 32; ++kk) {
            int k = seg * 32 + kk;
            float hv = (float)hs[row][k];
            p0 += hv * W2[k * 3 + 0];
            p1 += hv * W2[k * 3 + 1];
            p2 += hv * W2[k * 3 + 2];
        }
        part[row][seg][0] = p0; part[row][seg][1] = p1; part[row][seg][2] = p2;
    }
    __syncthreads();
    if (t < 192) {
        int row = t / 3, c = t - row * 3;
        int gr = tile + row;
        if (gr < N) {
            float a = b2[c];
            #pragma unroll
            for (int q = 0; q < 4; ++q) a += part[row][q][c];
            out[(size_t)gr * 3 + c] = a;
        }
    }
}

// ---------------- launch ----------------

extern "C" void kernel_launch(void* const* d_in, const int* in_sizes, int n_in,
                              void* d_out, int out_size, void* d_ws, size_t ws_size,
                              hipStream_t stream) {
    const int*   residue_p = (const int*)d_in[0];
    const float* pos_p     = (const float*)d_in[1];
    const int*   ei_p      = (const int*)d_in[2];
    const int*   batch_p   = (const int*)d_in[3];
    const int*   residue_m = (const int*)d_in[4];
    const float* pos_m     = (const float*)d_in[5];
    const int*   ei_m      = (const int*)d_in[6];
    const int*   batch_m   = (const int*)d_in[7];
    const float* W_p1 = (const float*)d_in[8];
    const float* b_p1 = (const float*)d_in[9];
    const float* W_p2 = (const float*)d_in[10];
    const float* b_p2 = (const float*)d_in[11];
    const float* W_m1 = (const float*)d_in[12];
    const float* b_m1 = (const float*)d_in[13];
    const float* W_m2 = (const float*)d_in[14];
    const float* b_m2 = (const float*)d_in[15];
    const float* W1   = (const float*)d_in[16];
    const float* b1   = (const float*)d_in[17];
    const float* W2   = (const float*)d_in[18];
    const float* b2   = (const float*)d_in[19];

    const int N_P = in_sizes[0];
    const int E_P = in_sizes[2] / 2;
    const int N_M = in_sizes[4];
    const int E_M = in_sizes[6] / 2;
    const int G = 64;

    char* ws = (char*)d_ws;
    size_t off = 0;
    auto alloc = [&](size_t bytes) {
        char* p = ws + off;
        off += (bytes + 511) & ~size_t(511);
        return p;
    };
    float*        bufA    = (float*)alloc((size_t)N_P * HID * 4);   // z (fp32)
    float*        bufB    = (float*)alloc((size_t)N_P * 24 * 4);    // z0
    __half*       x1h     = (__half*)alloc((size_t)N_P * HID * 2);  // x1 fp16
    int*          deg     = (int*)  alloc((size_t)N_P * 4);
    float*        dinv    = (float*)alloc((size_t)N_P * 4);
    float*        invd    = (float*)alloc((size_t)N_P * 4);
    int*          rowptr  = (int*)  alloc((size_t)(N_P + 1) * 4);
    int*          partials= (int*)  alloc(256 * 4);
    int*          bcursor = (int*)  alloc((NBMAX + 1) * 4);
    unsigned int* pairs   = (unsigned int*)alloc((size_t)E_P * 4);
    int*          csr_src = (int*)  alloc((size_t)E_P * 4);
    float*        psum    = (float*)alloc((size_t)G * HID * 4);
    int*          pcnt    = (int*)  alloc((size_t)G * 4);
    float*        ctxW    = (float*)alloc((size_t)G * HID * 4);
    f16*          Wp2t    = (f16*)  alloc(128 * 128 * 2);
    f16*          Wm2t    = (f16*)  alloc(128 * 128 * 2);
    f16*          W1at    = (f16*)  alloc(128 * 128 * 2);

    // weight prep (once, up front)
    k_prep_w<<<64, 256, 0, stream>>>(W_p2, W_m2, W1, Wp2t, Wm2t, W1at);

    auto run_branch = [&](const int* residue, const float* pos, const int* ei,
                          const float* Wl1, const float* bl1, int N, int E) {
        const int* srcp = ei;
        const int* dstp = ei + E;
        int NB = (N + 63) / 64;
        int nbp = (N + SCAN_BS - 1) / SCAN_BS;

        hipMemsetAsync(deg, 0, (size_t)N * 4, stream);
        k_count_deg<<<(E + 255) / 256, 256, 0, stream>>>(dstp, deg, E);
        k_deg_finalize<<<(N + 255) / 256, 256, 0, stream>>>(deg, dinv, invd, N);
        k_scan_partial<<<nbp, SCAN_TPB, 0, stream>>>(deg, partials, N);
        k_scan_root<<<1, SCAN_TPB, 0, stream>>>(partials, nbp);
        k_scan_final<<<nbp, SCAN_TPB, 0, stream>>>(deg, partials, rowptr, N);
        k_init_bcursor<<<(NB + 256) / 256, 256, 0, stream>>>(rowptr, bcursor, N, NB);
        k_tile_bin<<<(E + BIN_T - 1) / BIN_T, 256, 0, stream>>>(srcp, dstp, bcursor, pairs, E, NB);
        k_bucket_fill<<<NB, 256, 0, stream>>>(pairs, rowptr, csr_src, N);

        k_agg23<<<(N + 255) / 256, 256, 0, stream>>>(rowptr, csr_src, residue, pos,
                                                     dinv, invd, bufB, N);
        k_gemm24<<<(N + G24_ROWS - 1) / G24_ROWS, 256, 0, stream>>>(bufB, Wl1, bl1, x1h, N);
        k_agg128<<<(N + 3) / 4, 256, 0, stream>>>((const __half2*)x1h, rowptr, csr_src,
                                                  dinv, invd, bufA, N);
        // result: bufA (z, fp32)
    };

    // ---- protein branch ----
    run_branch(residue_p, pos_p, ei_p, W_p1, b_p1, N_P, E_P);
    hipMemsetAsync(psum, 0, (size_t)G * HID * 4, stream);
    hipMemsetAsync(pcnt, 0, (size_t)G * 4, stream);
    k_gemm_pool_mfma<<<(N_P + 63) / 64, 256, 0, stream>>>(bufA, Wp2t, b_p2, batch_p, psum, N_P);
    k_count_batch<<<256, 256, 0, stream>>>(batch_p, pcnt, N_P);
    k_ctxw_div<<<G, HID, 0, stream>>>(psum, pcnt, W1, b1, ctxW);

    // ---- micromolecule branch ----
    run_branch(residue_m, pos_m, ei_m, W_m1, b_m1, N_M, E_M);
    k_mm_tail_mfma<<<(N_M + 63) / 64, 256, 0, stream>>>(bufA, Wm2t, b_m2, batch_m, ctxW,
                                                        W1at, W2, b2, (float*)d_out, N_M);
}

// Round 7
// 431.880 us; speedup vs baseline: 5.5397x; 1.2449x over previous
//
#include <hip/hip_runtime.h>
#include <hip/hip_bf16.h>
#include <hip/hip_fp16.h>

#define HID 128
#define BIN_T 8192
#define NBMAX 1664   // max 64-node buckets (N <= 106496)

typedef _Float16 f16;
typedef __attribute__((ext_vector_type(4))) _Float16 f16x4;
typedef __attribute__((ext_vector_type(8))) _Float16 f16x8;
typedef __attribute__((ext_vector_type(4))) float f32x4;

// ---------------- bucket histogram (dst>>6) ----------------

__global__ void k_hist_bucket(const int* __restrict__ dst, int* __restrict__ bcount,
                              int E, int NB) {
    __shared__ int h[NBMAX];
    for (int i = threadIdx.x; i < NB; i += 256) h[i] = 0;
    __syncthreads();
    for (long long i = (long long)blockIdx.x * 256 + threadIdx.x; i < E;
         i += (long long)gridDim.x * 256)
        atomicAdd(&h[((unsigned)dst[i]) >> 6], 1);
    __syncthreads();
    for (int i = threadIdx.x; i < NB; i += 256)
        if (h[i]) atomicAdd(&bcount[i], h[i]);
}

// single-block exclusive scan over NB buckets -> boff, bcursor
__global__ void k_bucket_scan(const int* __restrict__ bcount, int* __restrict__ boff,
                              int* __restrict__ bcursor, int NB) {
    __shared__ int tt[256];
    int ts = threadIdx.x;
    int b0 = ts * 7;
    int loc[7]; int run = 0;
    #pragma unroll
    for (int k = 0; k < 7; ++k) {
        int b = b0 + k;
        int c = (b < NB) ? bcount[b] : 0;
        loc[k] = run; run += c;
    }
    tt[ts] = run;
    __syncthreads();
    int val = run;
    for (int off = 1; off < 256; off <<= 1) {
        int add = (ts >= off) ? tt[ts - off] : 0;
        __syncthreads();
        tt[ts] += add;
        __syncthreads();
    }
    int ebase = tt[ts] - val;
    #pragma unroll
    for (int k = 0; k < 7; ++k) {
        int b = b0 + k;
        if (b < NB) { boff[b] = ebase + loc[k]; bcursor[b] = ebase + loc[k]; }
    }
    if (ts == 255) boff[NB] = tt[255];
}

// ---------------- tile-sorted bucket binning (coalesced writes) ----------------
// pairs[slot] = src | (dst&63)<<26, grouped by bucket (dst>>6).

__global__ void k_tile_bin(const int* __restrict__ src, const int* __restrict__ dst,
                           int* __restrict__ bcursor, unsigned int* __restrict__ pairs,
                           int E, int NB) {
    __shared__ unsigned int dbuf[BIN_T];
    __shared__ unsigned short perm[BIN_T];
    __shared__ int hist[NBMAX];
    __shared__ int lbase[NBMAX];
    __shared__ int gbase[NBMAX];
    __shared__ int tt[256];
    int t = threadIdx.x;
    int tilebase = blockIdx.x * BIN_T;
    int n = min(BIN_T, E - tilebase);
    for (int i = t; i < NB; i += 256) hist[i] = 0;
    __syncthreads();
    for (int i = t; i < n; i += 256) {
        unsigned int d = (unsigned int)dst[tilebase + i];
        dbuf[i] = d;
        atomicAdd(&hist[d >> 6], 1);
    }
    __syncthreads();
    {
        int b0 = t * 7, loc[7], run = 0;
        #pragma unroll
        for (int k = 0; k < 7; ++k) {
            int b = b0 + k;
            int c = (b < NB) ? hist[b] : 0;
            loc[k] = run; run += c;
        }
        tt[t] = run;
        __syncthreads();
        int val = run;
        for (int off = 1; off < 256; off <<= 1) {
            int add = (t >= off) ? tt[t - off] : 0;
            __syncthreads();
            tt[t] += add;
            __syncthreads();
        }
        int ebase = tt[t] - val;
        #pragma unroll
        for (int k = 0; k < 7; ++k) {
            int b = b0 + k;
            if (b < NB) lbase[b] = ebase + loc[k];
        }
    }
    __syncthreads();
    for (int i = t; i < NB; i += 256) {
        int c = hist[i];
        gbase[i] = (c > 0) ? atomicAdd(&bcursor[i], c) : 0;
    }
    __syncthreads();
    for (int i = t; i < NB; i += 256) hist[i] = lbase[i];
    __syncthreads();
    for (int i = t; i < n; i += 256) {
        int b = (int)(dbuf[i] >> 6);
        int p = atomicAdd(&hist[b], 1);
        perm[p] = (unsigned short)i;
    }
    __syncthreads();
    for (int p = t; p < n; p += 256) {
        int li = perm[p];
        unsigned int d = dbuf[li];
        int b = (int)(d >> 6);
        int addr = gbase[b] + (p - lbase[b]);
        pairs[addr] = (unsigned int)src[tilebase + li] | ((d & 63u) << 26);
    }
}

// ---------------- bucket fill: degrees, dinv, rowptr, rec8, res8, csr ----------------

__global__ void k_bucket_fill2(const unsigned int* __restrict__ pairs,
                               const int* __restrict__ boff,
                               const int* __restrict__ residue, const float* __restrict__ pos,
                               int* __restrict__ csr_src, f16x4* __restrict__ rec8,
                               unsigned char* __restrict__ res8, float* __restrict__ dinvA,
                               int* __restrict__ rowptr, int N) {
    __shared__ int cnt[64];
    __shared__ int cur[64];
    int b = blockIdx.x, t = threadIdx.x, base = b * 64;
    if (t < 64) cnt[t] = 0;
    __syncthreads();
    int lo = boff[b], hi = boff[b + 1];
    for (int e = lo + t; e < hi; e += 256)
        atomicAdd(&cnt[pairs[e] >> 26], 1);
    __syncthreads();
    if (t < 64) {
        int off = 0;
        for (int k = 0; k < t; ++k) off += cnt[k];
        int node = base + t;
        if (node < N) {
            rowptr[node] = lo + off;
            if (node == N - 1) rowptr[N] = hi;
            float d = (float)cnt[t] + 1.0f;   // +1 self loop
            float di = 1.0f / sqrtf(d);
            dinvA[node] = di;
            float px = pos[node * 3 + 0], py = pos[node * 3 + 1], pz = pos[node * 3 + 2];
            f16x4 r;
            r[0] = (f16)di; r[1] = (f16)(di * px); r[2] = (f16)(di * py); r[3] = (f16)(di * pz);
            rec8[node] = r;
            res8[node] = (unsigned char)residue[node];
        }
        cur[t] = lo + off;
    }
    __syncthreads();
    for (int e = lo + t; e < hi; e += 256) {
        unsigned int pk = pairs[e];
        int slot = atomicAdd(&cur[pk >> 26], 1);
        csr_src[slot] = (int)(pk & 0x3FFFFFFu);
    }
}

// ---------------- fused layer-1: bucket aggregation (24-dim) + GEMM + premult ----------------
// z0_i = dinv_i*(sum_s y0_s + y0_i), y0 = dinv*[onehot,pos]
// x1 = relu(z0@W + b); store y1 = dinv*x1 fp16

__global__ __launch_bounds__(256) void k_l1_fused(
        const unsigned int* __restrict__ pairs, const int* __restrict__ boff,
        const f16x4* __restrict__ rec8, const unsigned char* __restrict__ res8,
        const float* __restrict__ W, const float* __restrict__ bias,
        const float* __restrict__ dinvA, f16* __restrict__ y1h, int N) {
    __shared__ float acc[64][25];
    __shared__ float Ws[23 * 128];
    __shared__ float sdv[64];
    int b = blockIdx.x, t = threadIdx.x, base = b * 64;
    for (int q = t; q < 64 * 25; q += 256) ((float*)acc)[q] = 0.f;
    for (int q = t; q < 23 * 128; q += 256) Ws[q] = W[q];
    if (t < 64 && base + t < N) sdv[t] = dinvA[base + t];
    __syncthreads();
    int lo = boff[b], hi = boff[b + 1];
    for (int e = lo + t; e < hi; e += 256) {
        unsigned int pk = pairs[e];
        int s = (int)(pk & 0x3FFFFFFu), dl = (int)(pk >> 26);
        f16x4 r = rec8[s];
        int rs = res8[s];
        atomicAdd(&acc[dl][rs], (float)r[0]);
        atomicAdd(&acc[dl][20], (float)r[1]);
        atomicAdd(&acc[dl][21], (float)r[2]);
        atomicAdd(&acc[dl][22], (float)r[3]);
    }
    __syncthreads();
    if (t < 64) {
        int node = base + t;
        if (node < N) {
            f16x4 r = rec8[node];
            acc[t][res8[node]] += (float)r[0];
            acc[t][20] += (float)r[1];
            acc[t][21] += (float)r[2];
            acc[t][22] += (float)r[3];
            float di = sdv[t];
            #pragma unroll
            for (int k = 0; k < 23; ++k) acc[t][k] *= di;
        }
    }
    __syncthreads();
    int j = t & 127, slot = t >> 7;
    float bj = bias[j];
    for (int r = slot * 32; r < slot * 32 + 32; ++r) {
        int node = base + r;
        if (node >= N) break;
        float a = bj;
        #pragma unroll
        for (int k = 0; k < 23; ++k) a += acc[r][k] * Ws[k * 128 + j];
        float y = fmaxf(a, 0.f) * sdv[r];
        y1h[(size_t)node * HID + j] = (f16)y;
    }
}

// ---------------- layer-2 aggregation: wave-per-node, premultiplied fp16 sums ----------------

__global__ void k_agg128y(const __half2* __restrict__ y1h, const int* __restrict__ rowptr,
                          const int* __restrict__ csr_src, const float* __restrict__ dinvA,
                          float* __restrict__ z, int N) {
    int gw = (int)(((long long)blockIdx.x * blockDim.x + threadIdx.x) >> 6);
    int lane = threadIdx.x & 63;
    if (gw >= N) return;
    int s0 = rowptr[gw], s1 = rowptr[gw + 1];
    float ax = 0.f, ay = 0.f;
    int e = s0;
    for (; e + 4 <= s1; e += 4) {
        int sA = csr_src[e], sB = csr_src[e + 1], sC = csr_src[e + 2], sD = csr_src[e + 3];
        float2 vA = __half22float2(y1h[(size_t)sA * 64 + lane]);
        float2 vB = __half22float2(y1h[(size_t)sB * 64 + lane]);
        float2 vC = __half22float2(y1h[(size_t)sC * 64 + lane]);
        float2 vD = __half22float2(y1h[(size_t)sD * 64 + lane]);
        ax += vA.x + vB.x; ay += vA.y + vB.y;
        ax += vC.x + vD.x; ay += vC.y + vD.y;
    }
    for (; e < s1; ++e) {
        float2 v = __half22float2(y1h[(size_t)csr_src[e] * 64 + lane]);
        ax += v.x; ay += v.y;
    }
    float2 vs = __half22float2(y1h[(size_t)gw * 64 + lane]);
    float di = dinvA[gw];
    float2 o; o.x = (ax + vs.x) * di; o.y = (ay + vs.y) * di;
    ((float2*)(z + (size_t)gw * HID))[lane] = o;
}

// ---------------- weight prep: fp16 transposed tables ----------------

__global__ void k_prep_w(const float* __restrict__ Wp2, const float* __restrict__ Wm2,
                         const float* __restrict__ W1,
                         f16* __restrict__ Wp2t, f16* __restrict__ Wm2t,
                         f16* __restrict__ W1at) {
    int idx = blockIdx.x * 256 + threadIdx.x;
    if (idx >= 128 * 128) return;
    int n = idx & 127, k = idx >> 7;
    Wp2t[n * 128 + k] = (f16)Wp2[k * 128 + n];
    Wm2t[n * 128 + k] = (f16)Wm2[k * 128 + n];
    W1at[n * 128 + k] = (f16)W1[k * 128 + n];
}

// ---------------- MFMA GEMM + fused mean-pool (protein x2) ----------------

__global__ __launch_bounds__(256) void k_gemm_pool_mfma(
        const float* __restrict__ Z, const f16* __restrict__ Wt,
        const float* __restrict__ b, const int* __restrict__ batch,
        float* __restrict__ psum, int N) {
    __shared__ float x2s[64][132];
    __shared__ int bsh[64];
    int tile = blockIdx.x * 64;
    int t = threadIdx.x, lane = t & 63, w = t >> 6;
    int lr = lane & 15, kb = lane >> 4;
    int zrow = min(tile + w * 16 + lr, N - 1);
    f16x8 afr[4];
    #pragma unroll
    for (int kc = 0; kc < 4; ++kc) {
        const float* p = Z + (size_t)zrow * HID + kc * 32 + kb * 8;
        float4 v0 = *(const float4*)p;
        float4 v1 = *(const float4*)(p + 4);
        f16x8 a;
        a[0] = (f16)v0.x; a[1] = (f16)v0.y; a[2] = (f16)v0.z; a[3] = (f16)v0.w;
        a[4] = (f16)v1.x; a[5] = (f16)v1.y; a[6] = (f16)v1.z; a[7] = (f16)v1.w;
        afr[kc] = a;
    }
    #pragma unroll
    for (int ct = 0; ct < 8; ++ct) {
        f32x4 acc = {0.f, 0.f, 0.f, 0.f};
        int col = ct * 16 + lr;
        const f16* wp = Wt + (size_t)col * HID + kb * 8;
        #pragma unroll
        for (int kc = 0; kc < 4; ++kc) {
            f16x8 bf = *(const f16x8*)(wp + kc * 32);
            acc = __builtin_amdgcn_mfma_f32_16x16x32_f16(afr[kc], bf, acc, 0, 0, 0);
        }
        float bj = b[col];
        #pragma unroll
        for (int r = 0; r < 4; ++r)
            x2s[w * 16 + kb * 4 + r][col] = fmaxf(acc[r] + bj, 0.f);
    }
    if (t < 64) bsh[t] = batch[min(tile + t, N - 1)];
    __syncthreads();
    int rows = min(64, N - tile);
    if (t < 128) {
        if (bsh[0] == bsh[rows - 1]) {
            float s = 0.f;
            for (int r = 0; r < rows; ++r) s += x2s[r][t];
            atomicAdd(&psum[bsh[0] * HID + t], s);
        } else {
            int cg = bsh[0]; float s = 0.f;
            for (int r = 0; r < rows; ++r) {
                int g = bsh[r];
                if (g != cg) { atomicAdd(&psum[cg * HID + t], s); s = 0.f; cg = g; }
                s += x2s[r][t];
            }
            atomicAdd(&psum[cg * HID + t], s);
        }
    }
}

// graph sizes via binary search (batch sorted)
__global__ void k_graph_sizes(const int* __restrict__ batch, int* __restrict__ pcnt, int N) {
    int g = threadIdx.x;
    if (g >= 64) return;
    int lo = 0, hi = N;
    while (lo < hi) { int mid = (lo + hi) >> 1; if (batch[mid] < g) lo = mid + 1; else hi = mid; }
    int a = lo;
    lo = 0; hi = N;
    while (lo < hi) { int mid = (lo + hi) >> 1; if (batch[mid] < g + 1) lo = mid + 1; else hi = mid; }
    pcnt[g] = lo - a;
}

// ctxW[g] = (psum[g]/cnt[g]) @ W1[128:,:] + b1
__global__ void k_ctxw_div(const float* __restrict__ psum, const int* __restrict__ pcnt,
                           const float* __restrict__ W1, const float* __restrict__ b1,
                           float* __restrict__ ctxW) {
    __shared__ float pr[128];
    int g = blockIdx.x, j = threadIdx.x;
    pr[j] = psum[g * HID + j] / fmaxf((float)pcnt[g], 1.f);
    __syncthreads();
    float a = b1[j];
    #pragma unroll 4
    for (int k = 0; k < HID; ++k) a += pr[k] * W1[(HID + k) * HID + j];
    ctxW[g * HID + j] = a;
}

// ---------------- MFMA mm tail: x2 -> h -> out, fused ----------------

__global__ __launch_bounds__(256) void k_mm_tail_mfma(
        const float* __restrict__ Z, const f16* __restrict__ Wm2t,
        const float* __restrict__ bm2, const int* __restrict__ batch,
        const float* __restrict__ ctxW, const f16* __restrict__ W1at,
        const float* __restrict__ W2, const float* __restrict__ b2,
        float* __restrict__ out, int N) {
    __shared__ f16 x2s[64][136];
    __shared__ f16 hs[64][136];
    __shared__ float part[64][4][3];
    int tile = blockIdx.x * 64;
    int t = threadIdx.x, lane = t & 63, w = t >> 6;
    int lr = lane & 15, kb = lane >> 4;
    {
        int zrow = min(tile + w * 16 + lr, N - 1);
        f16x8 afr[4];
        #pragma unroll
        for (int kc = 0; kc < 4; ++kc) {
            const float* p = Z + (size_t)zrow * HID + kc * 32 + kb * 8;
            float4 v0 = *(const float4*)p;
            float4 v1 = *(const float4*)(p + 4);
            f16x8 a;
            a[0] = (f16)v0.x; a[1] = (f16)v0.y; a[2] = (f16)v0.z; a[3] = (f16)v0.w;
            a[4] = (f16)v1.x; a[5] = (f16)v1.y; a[6] = (f16)v1.z; a[7] = (f16)v1.w;
            afr[kc] = a;
        }
        #pragma unroll
        for (int ct = 0; ct < 8; ++ct) {
            f32x4 acc = {0.f, 0.f, 0.f, 0.f};
            int col = ct * 16 + lr;
            const f16* wp = Wm2t + (size_t)col * HID + kb * 8;
            #pragma unroll
            for (int kc = 0; kc < 4; ++kc) {
                f16x8 bf = *(const f16x8*)(wp + kc * 32);
                acc = __builtin_amdgcn_mfma_f32_16x16x32_f16(afr[kc], bf, acc, 0, 0, 0);
            }
            float bj = bm2[col];
            #pragma unroll
            for (int r = 0; r < 4; ++r)
                x2s[w * 16 + kb * 4 + r][col] = (f16)fmaxf(acc[r] + bj, 0.f);
        }
    }
    __syncthreads();
    {
        f16x8 afr[4];
        #pragma unroll
        for (int kc = 0; kc < 4; ++kc)
            afr[kc] = *(const f16x8*)&x2s[w * 16 + lr][kc * 32 + kb * 8];
        int gidx[4];
        #pragma unroll
        for (int r = 0; r < 4; ++r)
            gidx[r] = batch[min(tile + w * 16 + kb * 4 + r, N - 1)];
        #pragma unroll
        for (int ct = 0; ct < 8; ++ct) {
            f32x4 acc = {0.f, 0.f, 0.f, 0.f};
            int col = ct * 16 + lr;
            const f16* wp = W1at + (size_t)col * HID + kb * 8;
            #pragma unroll
            for (int kc = 0; kc < 4; ++kc) {
                f16x8 bf = *(const f16x8*)(wp + kc * 32);
                acc = __builtin_amdgcn_mfma_f32_16x16x32_f16(afr[kc], bf, acc, 0, 0, 0);
            }
            #pragma unroll
            for (int r = 0; r < 4; ++r) {
                float cx = ctxW[gidx[r] * HID + col];
                hs[w * 16 + kb * 4 + r][col] = (f16)fmaxf(acc[r] + cx, 0.f);
            }
        }
    }
    __syncthreads();
    {
        int row = t >> 2, seg = t & 3;
        float p0 = 0.f, p1 = 0.f, p2 = 0.f;
        #pragma unroll
        for (int kk = 0; kk < 32; ++kk) {
            int k = seg * 32 + kk;
            float hv = (float)hs[row][k];
            p0 += hv * W2[k * 3 + 0];
            p1 += hv * W2[k * 3 + 1];
            p2 += hv * W2[k * 3 + 2];
        }
        part[row][seg][0] = p0; part[row][seg][1] = p1; part[row][seg][2] = p2;
    }
    __syncthreads();
    if (t < 192) {
        int row = t / 3, c = t - row * 3;
        int gr = tile + row;
        if (gr < N) {
            float a = b2[c];
            #pragma unroll
            for (int q = 0; q < 4; ++q) a += part[row][q][c];
            out[(size_t)gr * 3 + c] = a;
        }
    }
}

// ---------------- launch ----------------

extern "C" void kernel_launch(void* const* d_in, const int* in_sizes, int n_in,
                              void* d_out, int out_size, void* d_ws, size_t ws_size,
                              hipStream_t stream) {
    const int*   residue_p = (const int*)d_in[0];
    const float* pos_p     = (const float*)d_in[1];
    const int*   ei_p      = (const int*)d_in[2];
    const int*   batch_p   = (const int*)d_in[3];
    const int*   residue_m = (const int*)d_in[4];
    const float* pos_m     = (const float*)d_in[5];
    const int*   ei_m      = (const int*)d_in[6];
    const int*   batch_m   = (const int*)d_in[7];
    const float* W_p1 = (const float*)d_in[8];
    const float* b_p1 = (const float*)d_in[9];
    const float* W_p2 = (const float*)d_in[10];
    const float* b_p2 = (const float*)d_in[11];
    const float* W_m1 = (const float*)d_in[12];
    const float* b_m1 = (const float*)d_in[13];
    const float* W_m2 = (const float*)d_in[14];
    const float* b_m2 = (const float*)d_in[15];
    const float* W1   = (const float*)d_in[16];
    const float* b1   = (const float*)d_in[17];
    const float* W2   = (const float*)d_in[18];
    const float* b2   = (const float*)d_in[19];

    const int N_P = in_sizes[0];
    const int E_P = in_sizes[2] / 2;
    const int N_M = in_sizes[4];
    const int E_M = in_sizes[6] / 2;
    const int G = 64;

    char* ws = (char*)d_ws;
    size_t off = 0;
    auto alloc = [&](size_t bytes) {
        char* p = ws + off;
        off += (bytes + 511) & ~size_t(511);
        return p;
    };
    float*         bufA    = (float*)alloc((size_t)N_P * HID * 4);   // z (fp32)
    f16*           y1h     = (f16*)  alloc((size_t)N_P * HID * 2);   // y1 = dinv*x1 fp16
    f16x4*         rec8    = (f16x4*)alloc((size_t)N_P * 8);
    unsigned char* res8    = (unsigned char*)alloc((size_t)N_P);
    float*         dinvA   = (float*)alloc((size_t)N_P * 4);
    int*           rowptr  = (int*)  alloc((size_t)(N_P + 1) * 4);
    int*           bcount  = (int*)  alloc((NBMAX + 1) * 4);
    int*           boff    = (int*)  alloc((NBMAX + 1) * 4);
    int*           bcursor = (int*)  alloc((NBMAX + 1) * 4);
    unsigned int*  pairs   = (unsigned int*)alloc((size_t)E_P * 4);
    int*           csr_src = (int*)  alloc((size_t)E_P * 4);
    float*         psum    = (float*)alloc((size_t)G * HID * 4);
    int*           pcnt    = (int*)  alloc((size_t)G * 4);
    float*         ctxW    = (float*)alloc((size_t)G * HID * 4);
    f16*           Wp2t    = (f16*)  alloc(128 * 128 * 2);
    f16*           Wm2t    = (f16*)  alloc(128 * 128 * 2);
    f16*           W1at    = (f16*)  alloc(128 * 128 * 2);

    k_prep_w<<<64, 256, 0, stream>>>(W_p2, W_m2, W1, Wp2t, Wm2t, W1at);

    auto run_branch = [&](const int* residue, const float* pos, const int* ei,
                          const float* Wl1, const float* bl1, int N, int E) {
        const int* srcp = ei;
        const int* dstp = ei + E;
        int NB = (N + 63) / 64;

        hipMemsetAsync(bcount, 0, (size_t)NB * 4, stream);
        k_hist_bucket<<<256, 256, 0, stream>>>(dstp, bcount, E, NB);
        k_bucket_scan<<<1, 256, 0, stream>>>(bcount, boff, bcursor, NB);
        k_tile_bin<<<(E + BIN_T - 1) / BIN_T, 256, 0, stream>>>(srcp, dstp, bcursor, pairs, E, NB);
        k_bucket_fill2<<<NB, 256, 0, stream>>>(pairs, boff, residue, pos, csr_src,
                                               rec8, res8, dinvA, rowptr, N);
        k_l1_fused<<<NB, 256, 0, stream>>>(pairs, boff, rec8, res8, Wl1, bl1, dinvA, y1h, N);
        k_agg128y<<<(N + 3) / 4, 256, 0, stream>>>((const __half2*)y1h, rowptr, csr_src,
                                                   dinvA, bufA, N);
        // result: bufA (z, fp32)
    };

    // ---- protein branch ----
    run_branch(residue_p, pos_p, ei_p, W_p1, b_p1, N_P, E_P);
    hipMemsetAsync(psum, 0, (size_t)G * HID * 4, stream);
    k_gemm_pool_mfma<<<(N_P + 63) / 64, 256, 0, stream>>>(bufA, Wp2t, b_p2, batch_p, psum, N_P);
    k_graph_sizes<<<1, 64, 0, stream>>>(batch_p, pcnt, N_P);
    k_ctxw_div<<<G, HID, 0, stream>>>(psum, pcnt, W1, b1, ctxW);

    // ---- micromolecule branch ----
    run_branch(residue_m, pos_m, ei_m, W_m1, b_m1, N_M, E_M);
    k_mm_tail_mfma<<<(N_M + 63) / 64, 256, 0, stream>>>(bufA, Wm2t, b_m2, batch_m, ctxW,
                                                        W1at, W2, b2, (float*)d_out, N_M);
}

// Round 8
// 414.710 us; speedup vs baseline: 5.7690x; 1.0414x over previous
//
#include <hip/hip_runtime.h>
#include <hip/hip_bf16.h>
#include <hip/hip_fp16.h>

#define HID 128
#define BIN_T 8192
#define NBMAX 1664   // max 64-node buckets (N <= 106496)

typedef _Float16 f16;
typedef __attribute__((ext_vector_type(2))) _Float16 f16x2;
typedef __attribute__((ext_vector_type(4))) _Float16 f16x4;
typedef __attribute__((ext_vector_type(8))) _Float16 f16x8;
typedef __attribute__((ext_vector_type(4))) float f32x4;

// ---------------- bucket histogram (dst>>6) ----------------

__global__ void k_hist_bucket(const int* __restrict__ dst, int* __restrict__ bcount,
                              int E, int NB) {
    __shared__ int h[NBMAX];
    for (int i = threadIdx.x; i < NB; i += 256) h[i] = 0;
    __syncthreads();
    for (long long i = (long long)blockIdx.x * 256 + threadIdx.x; i < E;
         i += (long long)gridDim.x * 256)
        atomicAdd(&h[((unsigned)dst[i]) >> 6], 1);
    __syncthreads();
    for (int i = threadIdx.x; i < NB; i += 256)
        if (h[i]) atomicAdd(&bcount[i], h[i]);
}

// single-block exclusive scan over NB buckets -> boff, bcursor; re-zeros bcount
__global__ void k_bucket_scan(const int* __restrict__ bcount_in, int* __restrict__ bcount,
                              int* __restrict__ boff, int* __restrict__ bcursor, int NB) {
    __shared__ int tt[256];
    int ts = threadIdx.x;
    int b0 = ts * 7;
    int loc[7]; int run = 0;
    #pragma unroll
    for (int k = 0; k < 7; ++k) {
        int b = b0 + k;
        int c = (b < NB) ? bcount_in[b] : 0;
        loc[k] = run; run += c;
    }
    tt[ts] = run;
    __syncthreads();
    int val = run;
    for (int off = 1; off < 256; off <<= 1) {
        int add = (ts >= off) ? tt[ts - off] : 0;
        __syncthreads();
        tt[ts] += add;
        __syncthreads();
    }
    int ebase = tt[ts] - val;
    #pragma unroll
    for (int k = 0; k < 7; ++k) {
        int b = b0 + k;
        if (b < NB) {
            boff[b] = ebase + loc[k];
            bcursor[b] = ebase + loc[k];
            bcount[b] = 0;   // ready for next branch
        }
    }
    if (ts == 255) boff[NB] = tt[255];
}

// ---------------- tile-sorted bucket binning (coalesced writes) ----------------
// pairs[slot] = src | (dst&63)<<26, grouped by bucket (dst>>6).

__global__ void k_tile_bin(const int* __restrict__ src, const int* __restrict__ dst,
                           int* __restrict__ bcursor, unsigned int* __restrict__ pairs,
                           int E, int NB) {
    __shared__ unsigned int dbuf[BIN_T];
    __shared__ unsigned short perm[BIN_T];
    __shared__ int hist[NBMAX];
    __shared__ int lbase[NBMAX];
    __shared__ int gbase[NBMAX];
    __shared__ int tt[256];
    int t = threadIdx.x;
    int tilebase = blockIdx.x * BIN_T;
    int n = min(BIN_T, E - tilebase);
    for (int i = t; i < NB; i += 256) hist[i] = 0;
    __syncthreads();
    for (int i = t; i < n; i += 256) {
        unsigned int d = (unsigned int)dst[tilebase + i];
        dbuf[i] = d;
        atomicAdd(&hist[d >> 6], 1);
    }
    __syncthreads();
    {
        int b0 = t * 7, loc[7], run = 0;
        #pragma unroll
        for (int k = 0; k < 7; ++k) {
            int b = b0 + k;
            int c = (b < NB) ? hist[b] : 0;
            loc[k] = run; run += c;
        }
        tt[t] = run;
        __syncthreads();
        int val = run;
        for (int off = 1; off < 256; off <<= 1) {
            int add = (t >= off) ? tt[t - off] : 0;
            __syncthreads();
            tt[t] += add;
            __syncthreads();
        }
        int ebase = tt[t] - val;
        #pragma unroll
        for (int k = 0; k < 7; ++k) {
            int b = b0 + k;
            if (b < NB) lbase[b] = ebase + loc[k];
        }
    }
    __syncthreads();
    for (int i = t; i < NB; i += 256) {
        int c = hist[i];
        gbase[i] = (c > 0) ? atomicAdd(&bcursor[i], c) : 0;
    }
    __syncthreads();
    for (int i = t; i < NB; i += 256) hist[i] = lbase[i];
    __syncthreads();
    for (int i = t; i < n; i += 256) {
        int b = (int)(dbuf[i] >> 6);
        int p = atomicAdd(&hist[b], 1);
        perm[p] = (unsigned short)i;
    }
    __syncthreads();
    for (int p = t; p < n; p += 256) {
        int li = perm[p];
        unsigned int d = dbuf[li];
        int b = (int)(d >> 6);
        int addr = gbase[b] + (p - lbase[b]);
        pairs[addr] = (unsigned int)src[tilebase + li] | ((d & 63u) << 26);
    }
}

// ---------------- bucket fill: degrees, dinv, rowptr, rec8, res8, csr ----------------

__global__ void k_bucket_fill2(const unsigned int* __restrict__ pairs,
                               const int* __restrict__ boff,
                               const int* __restrict__ residue, const float* __restrict__ pos,
                               int* __restrict__ csr_src, f16x4* __restrict__ rec8,
                               unsigned char* __restrict__ res8, float* __restrict__ dinvA,
                               int* __restrict__ rowptr, int N) {
    __shared__ int cnt[64];
    __shared__ int cur[64];
    int b = blockIdx.x, t = threadIdx.x, base = b * 64;
    if (t < 64) cnt[t] = 0;
    __syncthreads();
    int lo = boff[b], hi = boff[b + 1];
    for (int e = lo + t; e < hi; e += 256)
        atomicAdd(&cnt[pairs[e] >> 26], 1);
    __syncthreads();
    if (t < 64) {
        int off = 0;
        for (int k = 0; k < t; ++k) off += cnt[k];
        int node = base + t;
        if (node < N) {
            rowptr[node] = lo + off;
            if (node == N - 1) rowptr[N] = hi;
            float d = (float)cnt[t] + 1.0f;   // +1 self loop
            float di = 1.0f / sqrtf(d);
            dinvA[node] = di;
            float px = pos[node * 3 + 0], py = pos[node * 3 + 1], pz = pos[node * 3 + 2];
            f16x4 r;
            r[0] = (f16)di; r[1] = (f16)(di * px); r[2] = (f16)(di * py); r[3] = (f16)(di * pz);
            rec8[node] = r;
            res8[node] = (unsigned char)residue[node];
        }
        cur[t] = lo + off;
    }
    __syncthreads();
    for (int e = lo + t; e < hi; e += 256) {
        unsigned int pk = pairs[e];
        int slot = atomicAdd(&cur[pk >> 26], 1);
        csr_src[slot] = (int)(pk & 0x3FFFFFFu);
    }
}

// ---------------- fused layer-1: bucket aggregation (24-dim) + GEMM + premult ----------------
// z0_i = dinv_i*(sum_s y0_s + y0_i), y0 = dinv*[onehot,pos]
// x1 = relu(z0@W + b); store y1 = dinv*x1 fp16

__global__ __launch_bounds__(256) void k_l1_fused(
        const unsigned int* __restrict__ pairs, const int* __restrict__ boff,
        const f16x4* __restrict__ rec8, const unsigned char* __restrict__ res8,
        const float* __restrict__ W, const float* __restrict__ bias,
        const float* __restrict__ dinvA, f16* __restrict__ y1h, int N) {
    __shared__ float acc[64][25];
    __shared__ float Ws[23 * 128];
    __shared__ float sdv[64];
    int b = blockIdx.x, t = threadIdx.x, base = b * 64;
    for (int q = t; q < 64 * 25; q += 256) ((float*)acc)[q] = 0.f;
    for (int q = t; q < 23 * 128; q += 256) Ws[q] = W[q];
    if (t < 64 && base + t < N) sdv[t] = dinvA[base + t];
    __syncthreads();
    int lo = boff[b], hi = boff[b + 1];
    for (int e = lo + t; e < hi; e += 256) {
        unsigned int pk = pairs[e];
        int s = (int)(pk & 0x3FFFFFFu), dl = (int)(pk >> 26);
        f16x4 r = rec8[s];
        int rs = res8[s];
        atomicAdd(&acc[dl][rs], (float)r[0]);
        atomicAdd(&acc[dl][20], (float)r[1]);
        atomicAdd(&acc[dl][21], (float)r[2]);
        atomicAdd(&acc[dl][22], (float)r[3]);
    }
    __syncthreads();
    if (t < 64) {
        int node = base + t;
        if (node < N) {
            f16x4 r = rec8[node];
            acc[t][res8[node]] += (float)r[0];
            acc[t][20] += (float)r[1];
            acc[t][21] += (float)r[2];
            acc[t][22] += (float)r[3];
            float di = sdv[t];
            #pragma unroll
            for (int k = 0; k < 23; ++k) acc[t][k] *= di;
        }
    }
    __syncthreads();
    int jj = (t & 63) * 2, slot = t >> 6;   // 4 slots x 16 rows
    float bj0 = bias[jj], bj1 = bias[jj + 1];
    for (int r = slot * 16; r < slot * 16 + 16; ++r) {
        int node = base + r;
        if (node >= N) break;
        float a0 = bj0, a1 = bj1;
        #pragma unroll
        for (int k = 0; k < 23; ++k) {
            float zv = acc[r][k];
            a0 += zv * Ws[k * 128 + jj];
            a1 += zv * Ws[k * 128 + jj + 1];
        }
        float dv = sdv[r];
        f16x2 o;
        o[0] = (f16)(fmaxf(a0, 0.f) * dv);
        o[1] = (f16)(fmaxf(a1, 0.f) * dv);
        *(f16x2*)&y1h[(size_t)node * HID + jj] = o;
    }
}

// ---------------- weight prep: fp16 transposed tables (+ zero bcount) ----------------

__global__ void k_prep_w(const float* __restrict__ Wp2, const float* __restrict__ Wm2,
                         const float* __restrict__ W1,
                         f16* __restrict__ Wp2t, f16* __restrict__ Wm2t,
                         f16* __restrict__ W1at, int* __restrict__ bcount) {
    int idx = blockIdx.x * 256 + threadIdx.x;
    if (idx <= NBMAX) bcount[idx] = 0;
    if (idx >= 128 * 128) return;
    int n = idx & 127, k = idx >> 7;
    Wp2t[n * 128 + k] = (f16)Wp2[k * 128 + n];
    Wm2t[n * 128 + k] = (f16)Wm2[k * 128 + n];
    W1at[n * 128 + k] = (f16)W1[k * 128 + n];
}

// graph sizes via binary search (batch sorted) + zero psum
__global__ void k_graph_sizes(const int* __restrict__ batch, int* __restrict__ pcnt,
                              float* __restrict__ psum, int N) {
    int t = blockIdx.x * 256 + threadIdx.x;
    if (t < 64 * HID) psum[t] = 0.f;
    if (t >= 64) return;
    int g = t;
    int lo = 0, hi = N;
    while (lo < hi) { int mid = (lo + hi) >> 1; if (batch[mid] < g) lo = mid + 1; else hi = mid; }
    int a = lo;
    lo = 0; hi = N;
    while (lo < hi) { int mid = (lo + hi) >> 1; if (batch[mid] < g + 1) lo = mid + 1; else hi = mid; }
    pcnt[g] = lo - a;
}

// ctxW[g] = (psum[g]/cnt[g]) @ W1[128:,:] + b1
__global__ void k_ctxw_div(const float* __restrict__ psum, const int* __restrict__ pcnt,
                           const float* __restrict__ W1, const float* __restrict__ b1,
                           float* __restrict__ ctxW) {
    __shared__ float pr[128];
    int g = blockIdx.x, j = threadIdx.x;
    pr[j] = psum[g * HID + j] / fmaxf((float)pcnt[g], 1.f);
    __syncthreads();
    float a = b1[j];
    #pragma unroll 4
    for (int k = 0; k < HID; ++k) a += pr[k] * W1[(HID + k) * HID + j];
    ctxW[g * HID + j] = a;
}

// ---------------- fused: per-lane A-frag aggregation ----------------
// Each lane (lr=lane&15, kb=lane>>4) owns node tile+w*16+lr, cols kc*32+kb*8..+7.
// acc = sum of y1 rows over edges; afr = f16((acc + self) * dinv) == A-fragment.

#define AGG_TO_AFR(afr_out)                                                          \
    int node = tile + w * 16 + lr;                                                   \
    int cn = min(node, N - 1);                                                       \
    int s0 = rowptr[cn], s1 = rowptr[cn + 1];                                        \
    float acc[4][8] = {};                                                            \
    int e = s0;                                                                      \
    for (; e + 2 <= s1; e += 2) {                                                    \
        int sA = csr_src[e], sB = csr_src[e + 1];                                    \
        const f16* pA = y1h + (size_t)sA * HID + kb * 8;                             \
        const f16* pB = y1h + (size_t)sB * HID + kb * 8;                             \
        f16x8 vA0 = *(const f16x8*)(pA + 0),  vA1 = *(const f16x8*)(pA + 32);        \
        f16x8 vA2 = *(const f16x8*)(pA + 64), vA3 = *(const f16x8*)(pA + 96);        \
        f16x8 vB0 = *(const f16x8*)(pB + 0),  vB1 = *(const f16x8*)(pB + 32);        \
        f16x8 vB2 = *(const f16x8*)(pB + 64), vB3 = *(const f16x8*)(pB + 96);        \
        _Pragma("unroll")                                                            \
        for (int j = 0; j < 8; ++j) {                                                \
            acc[0][j] += (float)vA0[j] + (float)vB0[j];                              \
            acc[1][j] += (float)vA1[j] + (float)vB1[j];                              \
            acc[2][j] += (float)vA2[j] + (float)vB2[j];                              \
            acc[3][j] += (float)vA3[j] + (float)vB3[j];                              \
        }                                                                            \
    }                                                                                \
    if (e < s1) {                                                                    \
        int sA = csr_src[e];                                                         \
        const f16* pA = y1h + (size_t)sA * HID + kb * 8;                             \
        f16x8 vA0 = *(const f16x8*)(pA + 0),  vA1 = *(const f16x8*)(pA + 32);        \
        f16x8 vA2 = *(const f16x8*)(pA + 64), vA3 = *(const f16x8*)(pA + 96);        \
        _Pragma("unroll")                                                            \
        for (int j = 0; j < 8; ++j) {                                                \
            acc[0][j] += (float)vA0[j];                                              \
            acc[1][j] += (float)vA1[j];                                              \
            acc[2][j] += (float)vA2[j];                                              \
            acc[3][j] += (float)vA3[j];                                              \
        }                                                                            \
    }                                                                                \
    {                                                                                \
        float di = dinvA[cn];                                                        \
        const f16* sp = y1h + (size_t)cn * HID + kb * 8;                             \
        _Pragma("unroll")                                                            \
        for (int kc = 0; kc < 4; ++kc) {                                             \
            f16x8 sv = *(const f16x8*)(sp + kc * 32);                                \
            f16x8 o;                                                                 \
            _Pragma("unroll")                                                        \
            for (int j = 0; j < 8; ++j)                                              \
                o[j] = (f16)((acc[kc][j] + (float)sv[j]) * di);                      \
            afr_out[kc] = o;                                                         \
        }                                                                            \
    }

// protein: agg -> x2 = relu(z@Wp2+b) -> fused mean-pool sum
__global__ __launch_bounds__(256) void k_agg_gemm_pool(
        const f16* __restrict__ y1h, const int* __restrict__ rowptr,
        const int* __restrict__ csr_src, const float* __restrict__ dinvA,
        const f16* __restrict__ Wt, const float* __restrict__ b,
        const int* __restrict__ batch, float* __restrict__ psum, int N) {
    __shared__ float x2s[64][132];
    __shared__ int bsh[64];
    int tile = blockIdx.x * 64;
    int t = threadIdx.x, lane = t & 63, w = t >> 6;
    int lr = lane & 15, kb = lane >> 4;
    f16x8 afr[4];
    AGG_TO_AFR(afr)
    #pragma unroll
    for (int ct = 0; ct < 8; ++ct) {
        f32x4 c4 = {0.f, 0.f, 0.f, 0.f};
        int col = ct * 16 + lr;
        const f16* wp = Wt + (size_t)col * HID + kb * 8;
        #pragma unroll
        for (int kc = 0; kc < 4; ++kc) {
            f16x8 bf = *(const f16x8*)(wp + kc * 32);
            c4 = __builtin_amdgcn_mfma_f32_16x16x32_f16(afr[kc], bf, c4, 0, 0, 0);
        }
        float bj = b[col];
        #pragma unroll
        for (int r = 0; r < 4; ++r)
            x2s[w * 16 + kb * 4 + r][col] = fmaxf(c4[r] + bj, 0.f);
    }
    if (t < 64) bsh[t] = batch[min(tile + t, N - 1)];
    __syncthreads();
    int rows = min(64, N - tile);
    if (t < 128) {
        if (bsh[0] == bsh[rows - 1]) {
            float s = 0.f;
            for (int r = 0; r < rows; ++r) s += x2s[r][t];
            atomicAdd(&psum[bsh[0] * HID + t], s);
        } else {
            int cg = bsh[0]; float s = 0.f;
            for (int r = 0; r < rows; ++r) {
                int g = bsh[r];
                if (g != cg) { atomicAdd(&psum[cg * HID + t], s); s = 0.f; cg = g; }
                s += x2s[r][t];
            }
            atomicAdd(&psum[cg * HID + t], s);
        }
    }
}

// mm: agg -> x2 -> h -> out, fully fused
__global__ __launch_bounds__(256) void k_agg_mm_tail(
        const f16* __restrict__ y1h, const int* __restrict__ rowptr,
        const int* __restrict__ csr_src, const float* __restrict__ dinvA,
        const f16* __restrict__ Wm2t, const float* __restrict__ bm2,
        const int* __restrict__ batch, const float* __restrict__ ctxW,
        const f16* __restrict__ W1at, const float* __restrict__ W2,
        const float* __restrict__ b2, float* __restrict__ out, int N) {
    __shared__ f16 x2s[64][136];
    __shared__ f16 hs[64][136];
    __shared__ float part[64][4][3];
    int tile = blockIdx.x * 64;
    int t = threadIdx.x, lane = t & 63, w = t >> 6;
    int lr = lane & 15, kb = lane >> 4;
    // phase 1: aggregate -> afr; x2 = relu(z @ Wm2 + bm2) -> LDS f16
    {
        f16x8 afr[4];
        AGG_TO_AFR(afr)
        #pragma unroll
        for (int ct = 0; ct < 8; ++ct) {
            f32x4 c4 = {0.f, 0.f, 0.f, 0.f};
            int col = ct * 16 + lr;
            const f16* wp = Wm2t + (size_t)col * HID + kb * 8;
            #pragma unroll
            for (int kc = 0; kc < 4; ++kc) {
                f16x8 bf = *(const f16x8*)(wp + kc * 32);
                c4 = __builtin_amdgcn_mfma_f32_16x16x32_f16(afr[kc], bf, c4, 0, 0, 0);
            }
            float bj = bm2[col];
            #pragma unroll
            for (int r = 0; r < 4; ++r)
                x2s[w * 16 + kb * 4 + r][col] = (f16)fmaxf(c4[r] + bj, 0.f);
        }
    }
    __syncthreads();
    // phase 2: h = relu(x2 @ W1a + ctxW[batch]) -> LDS f16
    {
        f16x8 afr[4];
        #pragma unroll
        for (int kc = 0; kc < 4; ++kc)
            afr[kc] = *(const f16x8*)&x2s[w * 16 + lr][kc * 32 + kb * 8];
        int gidx[4];
        #pragma unroll
        for (int r = 0; r < 4; ++r)
            gidx[r] = batch[min(tile + w * 16 + kb * 4 + r, N - 1)];
        #pragma unroll
        for (int ct = 0; ct < 8; ++ct) {
            f32x4 c4 = {0.f, 0.f, 0.f, 0.f};
            int col = ct * 16 + lr;
            const f16* wp = W1at + (size_t)col * HID + kb * 8;
            #pragma unroll
            for (int kc = 0; kc < 4; ++kc) {
                f16x8 bf = *(const f16x8*)(wp + kc * 32);
                c4 = __builtin_amdgcn_mfma_f32_16x16x32_f16(afr[kc], bf, c4, 0, 0, 0);
            }
            #pragma unroll
            for (int r = 0; r < 4; ++r) {
                float cx = ctxW[gidx[r] * HID + col];
                hs[w * 16 + kb * 4 + r][col] = (f16)fmaxf(c4[r] + cx, 0.f);
            }
        }
    }
    __syncthreads();
    // phase 3: out = h @ W2 + b2 (128->3)
    {
        int row = t >> 2, seg = t & 3;
        float p0 = 0.f, p1 = 0.f, p2 = 0.f;
        #pragma unroll
        for (int kk = 0; kk < 32; ++kk) {
            int k = seg * 32 + kk;
            float hv = (float)hs[row][k];
            p0 += hv * W2[k * 3 + 0];
            p1 += hv * W2[k * 3 + 1];
            p2 += hv * W2[k * 3 + 2];
        }
        part[row][seg][0] = p0; part[row][seg][1] = p1; part[row][seg][2] = p2;
    }
    __syncthreads();
    if (t < 192) {
        int row = t / 3, c = t - row * 3;
        int gr = tile + row;
        if (gr < N) {
            float a = b2[c];
            #pragma unroll
            for (int q = 0; q < 4; ++q) a += part[row][q][c];
            out[(size_t)gr * 3 + c] = a;
        }
    }
}

// ---------------- launch ----------------

extern "C" void kernel_launch(void* const* d_in, const int* in_sizes, int n_in,
                              void* d_out, int out_size, void* d_ws, size_t ws_size,
                              hipStream_t stream) {
    const int*   residue_p = (const int*)d_in[0];
    const float* pos_p     = (const float*)d_in[1];
    const int*   ei_p      = (const int*)d_in[2];
    const int*   batch_p   = (const int*)d_in[3];
    const int*   residue_m = (const int*)d_in[4];
    const float* pos_m     = (const float*)d_in[5];
    const int*   ei_m      = (const int*)d_in[6];
    const int*   batch_m   = (const int*)d_in[7];
    const float* W_p1 = (const float*)d_in[8];
    const float* b_p1 = (const float*)d_in[9];
    const float* W_p2 = (const float*)d_in[10];
    const float* b_p2 = (const float*)d_in[11];
    const float* W_m1 = (const float*)d_in[12];
    const float* b_m1 = (const float*)d_in[13];
    const float* W_m2 = (const float*)d_in[14];
    const float* b_m2 = (const float*)d_in[15];
    const float* W1   = (const float*)d_in[16];
    const float* b1   = (const float*)d_in[17];
    const float* W2   = (const float*)d_in[18];
    const float* b2   = (const float*)d_in[19];

    const int N_P = in_sizes[0];
    const int E_P = in_sizes[2] / 2;
    const int N_M = in_sizes[4];
    const int E_M = in_sizes[6] / 2;
    const int G = 64;

    char* ws = (char*)d_ws;
    size_t off = 0;
    auto alloc = [&](size_t bytes) {
        char* p = ws + off;
        off += (bytes + 511) & ~size_t(511);
        return p;
    };
    f16*           y1h     = (f16*)  alloc((size_t)N_P * HID * 2);   // y1 = dinv*x1 fp16
    f16x4*         rec8    = (f16x4*)alloc((size_t)N_P * 8);
    unsigned char* res8    = (unsigned char*)alloc((size_t)N_P);
    float*         dinvA   = (float*)alloc((size_t)N_P * 4);
    int*           rowptr  = (int*)  alloc((size_t)(N_P + 1) * 4);
    int*           bcount  = (int*)  alloc((NBMAX + 1) * 4);
    int*           boff    = (int*)  alloc((NBMAX + 1) * 4);
    int*           bcursor = (int*)  alloc((NBMAX + 1) * 4);
    unsigned int*  pairs   = (unsigned int*)alloc((size_t)E_P * 4);
    int*           csr_src = (int*)  alloc((size_t)E_P * 4);
    float*         psum    = (float*)alloc((size_t)G * HID * 4);
    int*           pcnt    = (int*)  alloc((size_t)G * 4);
    float*         ctxW    = (float*)alloc((size_t)G * HID * 4);
    f16*           Wp2t    = (f16*)  alloc(128 * 128 * 2);
    f16*           Wm2t    = (f16*)  alloc(128 * 128 * 2);
    f16*           W1at    = (f16*)  alloc(128 * 128 * 2);

    k_prep_w<<<64, 256, 0, stream>>>(W_p2, W_m2, W1, Wp2t, Wm2t, W1at, bcount);
    k_graph_sizes<<<32, 256, 0, stream>>>(batch_p, pcnt, psum, N_P);

    auto build_graph = [&](const int* residue, const float* pos, const int* ei,
                           const float* Wl1, const float* bl1, int N, int E) {
        const int* srcp = ei;
        const int* dstp = ei + E;
        int NB = (N + 63) / 64;
        k_hist_bucket<<<256, 256, 0, stream>>>(dstp, bcount, E, NB);
        k_bucket_scan<<<1, 256, 0, stream>>>(bcount, bcount, boff, bcursor, NB);
        k_tile_bin<<<(E + BIN_T - 1) / BIN_T, 256, 0, stream>>>(srcp, dstp, bcursor, pairs, E, NB);
        k_bucket_fill2<<<NB, 256, 0, stream>>>(pairs, boff, residue, pos, csr_src,
                                               rec8, res8, dinvA, rowptr, N);
        k_l1_fused<<<NB, 256, 0, stream>>>(pairs, boff, rec8, res8, Wl1, bl1, dinvA, y1h, N);
    };

    // ---- protein branch ----
    build_graph(residue_p, pos_p, ei_p, W_p1, b_p1, N_P, E_P);
    k_agg_gemm_pool<<<(N_P + 63) / 64, 256, 0, stream>>>(y1h, rowptr, csr_src, dinvA,
                                                         Wp2t, b_p2, batch_p, psum, N_P);
    k_ctxw_div<<<G, HID, 0, stream>>>(psum, pcnt, W1, b1, ctxW);

    // ---- micromolecule branch ----
    build_graph(residue_m, pos_m, ei_m, W_m1, b_m1, N_M, E_M);
    k_agg_mm_tail<<<(N_M + 63) / 64, 256, 0, stream>>>(y1h, rowptr, csr_src, dinvA,
                                                       Wm2t, b_m2, batch_m, ctxW,
                                                       W1at, W2, b2, (float*)d_out, N_M);
}

// Round 9
// 409.832 us; speedup vs baseline: 5.8377x; 1.0119x over previous
//
#include <hip/hip_runtime.h>
#include <hip/hip_bf16.h>
#include <hip/hip_fp16.h>

#define HID 128
#define BIN_T 8192
#define NBMAX 1664   // max 64-node buckets (N <= 106496)

typedef _Float16 f16;
typedef __attribute__((ext_vector_type(2))) _Float16 f16x2;
typedef __attribute__((ext_vector_type(4))) _Float16 f16x4;
typedef __attribute__((ext_vector_type(8))) _Float16 f16x8;
typedef __attribute__((ext_vector_type(4))) float f32x4;

// ---------------- bucket histogram (dst>>6) ----------------

__global__ void k_hist_bucket(const int* __restrict__ dst, int* __restrict__ bcount,
                              int E, int NB) {
    __shared__ int h[NBMAX];
    for (int i = threadIdx.x; i < NB; i += 256) h[i] = 0;
    __syncthreads();
    for (long long i = (long long)blockIdx.x * 256 + threadIdx.x; i < E;
         i += (long long)gridDim.x * 256)
        atomicAdd(&h[((unsigned)dst[i]) >> 6], 1);
    __syncthreads();
    for (int i = threadIdx.x; i < NB; i += 256)
        if (h[i]) atomicAdd(&bcount[i], h[i]);
}

// single-block exclusive scan over NB buckets -> boff, bcursor; re-zeros bcount
__global__ void k_bucket_scan(const int* __restrict__ bcount_in, int* __restrict__ bcount,
                              int* __restrict__ boff, int* __restrict__ bcursor, int NB) {
    __shared__ int tt[256];
    int ts = threadIdx.x;
    int b0 = ts * 7;
    int loc[7]; int run = 0;
    #pragma unroll
    for (int k = 0; k < 7; ++k) {
        int b = b0 + k;
        int c = (b < NB) ? bcount_in[b] : 0;
        loc[k] = run; run += c;
    }
    tt[ts] = run;
    __syncthreads();
    int val = run;
    for (int off = 1; off < 256; off <<= 1) {
        int add = (ts >= off) ? tt[ts - off] : 0;
        __syncthreads();
        tt[ts] += add;
        __syncthreads();
    }
    int ebase = tt[ts] - val;
    #pragma unroll
    for (int k = 0; k < 7; ++k) {
        int b = b0 + k;
        if (b < NB) {
            boff[b] = ebase + loc[k];
            bcursor[b] = ebase + loc[k];
            bcount[b] = 0;   // ready for next branch
        }
    }
    if (ts == 255) boff[NB] = tt[255];
}

// ---------------- tile-sorted bucket binning (coalesced writes) ----------------
// pairs[slot] = src | (dst&63)<<26, grouped by bucket (dst>>6).

__global__ void k_tile_bin(const int* __restrict__ src, const int* __restrict__ dst,
                           int* __restrict__ bcursor, unsigned int* __restrict__ pairs,
                           int E, int NB) {
    __shared__ unsigned int dbuf[BIN_T];
    __shared__ unsigned short perm[BIN_T];
    __shared__ int hist[NBMAX];
    __shared__ int lbase[NBMAX];
    __shared__ int gbase[NBMAX];
    __shared__ int tt[256];
    int t = threadIdx.x;
    int tilebase = blockIdx.x * BIN_T;
    int n = min(BIN_T, E - tilebase);
    for (int i = t; i < NB; i += 256) hist[i] = 0;
    __syncthreads();
    for (int i = t; i < n; i += 256) {
        unsigned int d = (unsigned int)dst[tilebase + i];
        dbuf[i] = d;
        atomicAdd(&hist[d >> 6], 1);
    }
    __syncthreads();
    {
        int b0 = t * 7, loc[7], run = 0;
        #pragma unroll
        for (int k = 0; k < 7; ++k) {
            int b = b0 + k;
            int c = (b < NB) ? hist[b] : 0;
            loc[k] = run; run += c;
        }
        tt[t] = run;
        __syncthreads();
        int val = run;
        for (int off = 1; off < 256; off <<= 1) {
            int add = (t >= off) ? tt[t - off] : 0;
            __syncthreads();
            tt[t] += add;
            __syncthreads();
        }
        int ebase = tt[t] - val;
        #pragma unroll
        for (int k = 0; k < 7; ++k) {
            int b = b0 + k;
            if (b < NB) lbase[b] = ebase + loc[k];
        }
    }
    __syncthreads();
    for (int i = t; i < NB; i += 256) {
        int c = hist[i];
        gbase[i] = (c > 0) ? atomicAdd(&bcursor[i], c) : 0;
    }
    __syncthreads();
    for (int i = t; i < NB; i += 256) hist[i] = lbase[i];
    __syncthreads();
    for (int i = t; i < n; i += 256) {
        int b = (int)(dbuf[i] >> 6);
        int p = atomicAdd(&hist[b], 1);
        perm[p] = (unsigned short)i;
    }
    __syncthreads();
    for (int p = t; p < n; p += 256) {
        int li = perm[p];
        unsigned int d = dbuf[li];
        int b = (int)(d >> 6);
        int addr = gbase[b] + (p - lbase[b]);
        pairs[addr] = (unsigned int)src[tilebase + li] | ((d & 63u) << 26);
    }
}

// ---------------- bucket fill: degrees, dinv, rowptr, rec8, res8, csr ----------------

__global__ void k_bucket_fill2(const unsigned int* __restrict__ pairs,
                               const int* __restrict__ boff,
                               const int* __restrict__ residue, const float* __restrict__ pos,
                               int* __restrict__ csr_src, f16x4* __restrict__ rec8,
                               unsigned char* __restrict__ res8, float* __restrict__ dinvA,
                               int* __restrict__ rowptr, int N) {
    __shared__ int cnt[64];
    __shared__ int cur[64];
    int b = blockIdx.x, t = threadIdx.x, base = b * 64;
    if (t < 64) cnt[t] = 0;
    __syncthreads();
    int lo = boff[b], hi = boff[b + 1];
    for (int e = lo + t; e < hi; e += 256)
        atomicAdd(&cnt[pairs[e] >> 26], 1);
    __syncthreads();
    if (t < 64) {
        int off = 0;
        for (int k = 0; k < t; ++k) off += cnt[k];
        int node = base + t;
        if (node < N) {
            rowptr[node] = lo + off;
            if (node == N - 1) rowptr[N] = hi;
            float d = (float)cnt[t] + 1.0f;   // +1 self loop
            float di = 1.0f / sqrtf(d);
            dinvA[node] = di;
            float px = pos[node * 3 + 0], py = pos[node * 3 + 1], pz = pos[node * 3 + 2];
            f16x4 r;
            r[0] = (f16)di; r[1] = (f16)(di * px); r[2] = (f16)(di * py); r[3] = (f16)(di * pz);
            rec8[node] = r;
            res8[node] = (unsigned char)residue[node];
        }
        cur[t] = lo + off;
    }
    __syncthreads();
    for (int e = lo + t; e < hi; e += 256) {
        unsigned int pk = pairs[e];
        int slot = atomicAdd(&cur[pk >> 26], 1);
        csr_src[slot] = (int)(pk & 0x3FFFFFFu);
    }
}

// ---------------- fused layer-1: bucket aggregation (24-dim) + GEMM + premult ----------------

__global__ __launch_bounds__(256) void k_l1_fused(
        const unsigned int* __restrict__ pairs, const int* __restrict__ boff,
        const f16x4* __restrict__ rec8, const unsigned char* __restrict__ res8,
        const float* __restrict__ W, const float* __restrict__ bias,
        const float* __restrict__ dinvA, f16* __restrict__ y1h, int N) {
    __shared__ float acc[64][25];
    __shared__ float Ws[23 * 128];
    __shared__ float sdv[64];
    int b = blockIdx.x, t = threadIdx.x, base = b * 64;
    for (int q = t; q < 64 * 25; q += 256) ((float*)acc)[q] = 0.f;
    for (int q = t; q < 23 * 128; q += 256) Ws[q] = W[q];
    if (t < 64 && base + t < N) sdv[t] = dinvA[base + t];
    __syncthreads();
    int lo = boff[b], hi = boff[b + 1];
    for (int e = lo + t; e < hi; e += 256) {
        unsigned int pk = pairs[e];
        int s = (int)(pk & 0x3FFFFFFu), dl = (int)(pk >> 26);
        f16x4 r = rec8[s];
        int rs = res8[s];
        atomicAdd(&acc[dl][rs], (float)r[0]);
        atomicAdd(&acc[dl][20], (float)r[1]);
        atomicAdd(&acc[dl][21], (float)r[2]);
        atomicAdd(&acc[dl][22], (float)r[3]);
    }
    __syncthreads();
    if (t < 64) {
        int node = base + t;
        if (node < N) {
            f16x4 r = rec8[node];
            acc[t][res8[node]] += (float)r[0];
            acc[t][20] += (float)r[1];
            acc[t][21] += (float)r[2];
            acc[t][22] += (float)r[3];
            float di = sdv[t];
            #pragma unroll
            for (int k = 0; k < 23; ++k) acc[t][k] *= di;
        }
    }
    __syncthreads();
    int jj = (t & 63) * 2, slot = t >> 6;   // 4 slots x 16 rows
    float bj0 = bias[jj], bj1 = bias[jj + 1];
    for (int r = slot * 16; r < slot * 16 + 16; ++r) {
        int node = base + r;
        if (node >= N) break;
        float a0 = bj0, a1 = bj1;
        #pragma unroll
        for (int k = 0; k < 23; ++k) {
            float zv = acc[r][k];
            a0 += zv * Ws[k * 128 + jj];
            a1 += zv * Ws[k * 128 + jj + 1];
        }
        float dv = sdv[r];
        f16x2 o;
        o[0] = (f16)(fmaxf(a0, 0.f) * dv);
        o[1] = (f16)(fmaxf(a1, 0.f) * dv);
        *(f16x2*)&y1h[(size_t)node * HID + jj] = o;
    }
}

// ---------------- weight prep: fp16 transposed tables (+ zero bcount) ----------------

__global__ void k_prep_w(const float* __restrict__ Wp2, const float* __restrict__ Wm2,
                         const float* __restrict__ W1,
                         f16* __restrict__ Wp2t, f16* __restrict__ Wm2t,
                         f16* __restrict__ W1at, int* __restrict__ bcount) {
    int idx = blockIdx.x * 256 + threadIdx.x;
    if (idx <= NBMAX) bcount[idx] = 0;
    if (idx >= 128 * 128) return;
    int n = idx & 127, k = idx >> 7;
    Wp2t[n * 128 + k] = (f16)Wp2[k * 128 + n];
    Wm2t[n * 128 + k] = (f16)Wm2[k * 128 + n];
    W1at[n * 128 + k] = (f16)W1[k * 128 + n];
}

// graph sizes via binary search (batch sorted) + zero psum
__global__ void k_graph_sizes(const int* __restrict__ batch, int* __restrict__ pcnt,
                              float* __restrict__ psum, int N) {
    int t = blockIdx.x * 256 + threadIdx.x;
    if (t < 64 * HID) psum[t] = 0.f;
    if (t >= 64) return;
    int g = t;
    int lo = 0, hi = N;
    while (lo < hi) { int mid = (lo + hi) >> 1; if (batch[mid] < g) lo = mid + 1; else hi = mid; }
    int a = lo;
    lo = 0; hi = N;
    while (lo < hi) { int mid = (lo + hi) >> 1; if (batch[mid] < g + 1) lo = mid + 1; else hi = mid; }
    pcnt[g] = lo - a;
}

// ctxW[g] = (psum[g]/cnt[g]) @ W1[128:,:] + b1
__global__ void k_ctxw_div(const float* __restrict__ psum, const int* __restrict__ pcnt,
                           const float* __restrict__ W1, const float* __restrict__ b1,
                           float* __restrict__ ctxW) {
    __shared__ float pr[128];
    int g = blockIdx.x, j = threadIdx.x;
    pr[j] = psum[g * HID + j] / fmaxf((float)pcnt[g], 1.f);
    __syncthreads();
    float a = b1[j];
    #pragma unroll 4
    for (int k = 0; k < HID; ++k) a += pr[k] * W1[(HID + k) * HID + j];
    ctxW[g * HID + j] = a;
}

// ---------------- fused: per-lane A-frag aggregation ----------------
// Each lane (lr=lane&15, kb=lane>>4) owns node tile+w*16+lr, cols kc*32+kb*8..+7.

#define AGG_TO_AFR(afr_out)                                                          \
    int node = tile + w * 16 + lr;                                                   \
    int cn = min(node, N - 1);                                                       \
    int s0 = rowptr[cn], s1 = rowptr[cn + 1];                                        \
    float acc[4][8] = {};                                                            \
    int e = s0;                                                                      \
    for (; e + 2 <= s1; e += 2) {                                                    \
        int sA = csr_src[e], sB = csr_src[e + 1];                                    \
        const f16* pA = y1h + (size_t)sA * HID + kb * 8;                             \
        const f16* pB = y1h + (size_t)sB * HID + kb * 8;                             \
        f16x8 vA0 = *(const f16x8*)(pA + 0),  vA1 = *(const f16x8*)(pA + 32);        \
        f16x8 vA2 = *(const f16x8*)(pA + 64), vA3 = *(const f16x8*)(pA + 96);        \
        f16x8 vB0 = *(const f16x8*)(pB + 0),  vB1 = *(const f16x8*)(pB + 32);        \
        f16x8 vB2 = *(const f16x8*)(pB + 64), vB3 = *(const f16x8*)(pB + 96);        \
        _Pragma("unroll")                                                            \
        for (int j = 0; j < 8; ++j) {                                                \
            acc[0][j] += (float)vA0[j] + (float)vB0[j];                              \
            acc[1][j] += (float)vA1[j] + (float)vB1[j];                              \
            acc[2][j] += (float)vA2[j] + (float)vB2[j];                              \
            acc[3][j] += (float)vA3[j] + (float)vB3[j];                              \
        }                                                                            \
    }                                                                                \
    if (e < s1) {                                                                    \
        int sA = csr_src[e];                                                         \
        const f16* pA = y1h + (size_t)sA * HID + kb * 8;                             \
        f16x8 vA0 = *(const f16x8*)(pA + 0),  vA1 = *(const f16x8*)(pA + 32);        \
        f16x8 vA2 = *(const f16x8*)(pA + 64), vA3 = *(const f16x8*)(pA + 96);        \
        _Pragma("unroll")                                                            \
        for (int j = 0; j < 8; ++j) {                                                \
            acc[0][j] += (float)vA0[j];                                              \
            acc[1][j] += (float)vA1[j];                                              \
            acc[2][j] += (float)vA2[j];                                              \
            acc[3][j] += (float)vA3[j];                                              \
        }                                                                            \
    }                                                                                \
    {                                                                                \
        float di = dinvA[cn];                                                        \
        const f16* sp = y1h + (size_t)cn * HID + kb * 8;                             \
        _Pragma("unroll")                                                            \
        for (int kc = 0; kc < 4; ++kc) {                                             \
            f16x8 sv = *(const f16x8*)(sp + kc * 32);                                \
            f16x8 o;                                                                 \
            _Pragma("unroll")                                                        \
            for (int j = 0; j < 8; ++j)                                              \
                o[j] = (f16)((acc[kc][j] + (float)sv[j]) * di);                      \
            afr_out[kc] = o;                                                         \
        }                                                                            \
    }

// protein: agg -> x2 = relu(z@Wp2+b) -> register pool -> psum
__global__ __launch_bounds__(256) void k_agg_gemm_pool(
        const f16* __restrict__ y1h, const int* __restrict__ rowptr,
        const int* __restrict__ csr_src, const float* __restrict__ dinvA,
        const f16* __restrict__ Wt, const float* __restrict__ b,
        const int* __restrict__ batch, float* __restrict__ psum, int N) {
    __shared__ float red[4][128];
    int tile = blockIdx.x * 64;
    int t = threadIdx.x, lane = t & 63, w = t >> 6;
    int lr = lane & 15, kb = lane >> 4;
    int g0 = batch[tile];
    bool uni = (tile + 63 < N) && (g0 == batch[tile + 63]);
    int gr[4]; bool val[4];
    if (!uni) {
        #pragma unroll
        for (int r = 0; r < 4; ++r) {
            int row = tile + w * 16 + kb * 4 + r;
            val[r] = row < N;
            gr[r] = batch[min(row, N - 1)];
        }
    }
    f16x8 afr[4];
    AGG_TO_AFR(afr)
    float ps[8];
    #pragma unroll
    for (int ct = 0; ct < 8; ++ct) ps[ct] = 0.f;
    #pragma unroll
    for (int ct = 0; ct < 8; ++ct) {
        f32x4 c4 = {0.f, 0.f, 0.f, 0.f};
        int col = ct * 16 + lr;
        const f16* wp = Wt + (size_t)col * HID + kb * 8;
        #pragma unroll
        for (int kc = 0; kc < 4; ++kc) {
            f16x8 bf = *(const f16x8*)(wp + kc * 32);
            c4 = __builtin_amdgcn_mfma_f32_16x16x32_f16(afr[kc], bf, c4, 0, 0, 0);
        }
        float bj = b[col];
        if (uni) {
            #pragma unroll
            for (int r = 0; r < 4; ++r) ps[ct] += fmaxf(c4[r] + bj, 0.f);
        } else {
            #pragma unroll
            for (int r = 0; r < 4; ++r)
                if (val[r]) atomicAdd(&psum[gr[r] * HID + col], fmaxf(c4[r] + bj, 0.f));
        }
    }
    if (uni) {
        #pragma unroll
        for (int ct = 0; ct < 8; ++ct) {
            ps[ct] += __shfl_xor(ps[ct], 16);
            ps[ct] += __shfl_xor(ps[ct], 32);
        }
        if (kb == 0) {
            #pragma unroll
            for (int ct = 0; ct < 8; ++ct) red[w][ct * 16 + lr] = ps[ct];
        }
        __syncthreads();
        if (t < 128) {
            float s = red[0][t] + red[1][t] + red[2][t] + red[3][t];
            atomicAdd(&psum[g0 * HID + t], s);
        }
    }
}

// mm: agg -> x2 -> h -> out, fully fused, no block barrier
__global__ __launch_bounds__(256) void k_agg_mm_tail(
        const f16* __restrict__ y1h, const int* __restrict__ rowptr,
        const int* __restrict__ csr_src, const float* __restrict__ dinvA,
        const f16* __restrict__ Wm2t, const float* __restrict__ bm2,
        const int* __restrict__ batch, const float* __restrict__ ctxW,
        const f16* __restrict__ W1at, const float* __restrict__ W2,
        const float* __restrict__ b2, float* __restrict__ out, int N) {
    __shared__ f16 x2s[64][136];
    int tile = blockIdx.x * 64;
    int t = threadIdx.x, lane = t & 63, w = t >> 6;
    int lr = lane & 15, kb = lane >> 4;
    // phase 1: aggregate -> afr; x2 = relu(z @ Wm2 + bm2) -> LDS f16 (wave-local rows)
    {
        f16x8 afr[4];
        AGG_TO_AFR(afr)
        #pragma unroll
        for (int ct = 0; ct < 8; ++ct) {
            f32x4 c4 = {0.f, 0.f, 0.f, 0.f};
            int col = ct * 16 + lr;
            const f16* wp = Wm2t + (size_t)col * HID + kb * 8;
            #pragma unroll
            for (int kc = 0; kc < 4; ++kc) {
                f16x8 bf = *(const f16x8*)(wp + kc * 32);
                c4 = __builtin_amdgcn_mfma_f32_16x16x32_f16(afr[kc], bf, c4, 0, 0, 0);
            }
            float bj = bm2[col];
            #pragma unroll
            for (int r = 0; r < 4; ++r)
                x2s[w * 16 + kb * 4 + r][col] = (f16)fmaxf(c4[r] + bj, 0.f);
        }
    }
    // wave-local LDS fence (phase 1 writes -> phase 2 reads are same-wave rows)
    asm volatile("s_waitcnt lgkmcnt(0)" ::: "memory");
    __builtin_amdgcn_sched_barrier(0);
    // phase 2+3: h = relu(x2 @ W1a + ctxW[batch]); out partials in registers
    {
        f16x8 afr[4];
        #pragma unroll
        for (int kc = 0; kc < 4; ++kc)
            afr[kc] = *(const f16x8*)&x2s[w * 16 + lr][kc * 32 + kb * 8];
        int gidx[4];
        #pragma unroll
        for (int r = 0; r < 4; ++r)
            gidx[r] = batch[min(tile + w * 16 + kb * 4 + r, N - 1)];
        float po[4][3] = {};
        #pragma unroll
        for (int ct = 0; ct < 8; ++ct) {
            f32x4 c4 = {0.f, 0.f, 0.f, 0.f};
            int col = ct * 16 + lr;
            const f16* wp = W1at + (size_t)col * HID + kb * 8;
            #pragma unroll
            for (int kc = 0; kc < 4; ++kc) {
                f16x8 bf = *(const f16x8*)(wp + kc * 32);
                c4 = __builtin_amdgcn_mfma_f32_16x16x32_f16(afr[kc], bf, c4, 0, 0, 0);
            }
            float w0 = W2[col * 3 + 0], w1 = W2[col * 3 + 1], w2 = W2[col * 3 + 2];
            #pragma unroll
            for (int r = 0; r < 4; ++r) {
                float h = fmaxf(c4[r] + ctxW[gidx[r] * HID + col], 0.f);
                po[r][0] += h * w0;
                po[r][1] += h * w1;
                po[r][2] += h * w2;
            }
        }
        // reduce over the 16 lr-lanes (cols)
        #pragma unroll
        for (int m = 1; m < 16; m <<= 1) {
            #pragma unroll
            for (int r = 0; r < 4; ++r) {
                po[r][0] += __shfl_xor(po[r][0], m);
                po[r][1] += __shfl_xor(po[r][1], m);
                po[r][2] += __shfl_xor(po[r][2], m);
            }
        }
        if (lr == 0) {
            #pragma unroll
            for (int r = 0; r < 4; ++r) {
                int row = tile + w * 16 + kb * 4 + r;
                if (row < N) {
                    out[(size_t)row * 3 + 0] = po[r][0] + b2[0];
                    out[(size_t)row * 3 + 1] = po[r][1] + b2[1];
                    out[(size_t)row * 3 + 2] = po[r][2] + b2[2];
                }
            }
        }
    }
}

// ---------------- launch ----------------

extern "C" void kernel_launch(void* const* d_in, const int* in_sizes, int n_in,
                              void* d_out, int out_size, void* d_ws, size_t ws_size,
                              hipStream_t stream) {
    const int*   residue_p = (const int*)d_in[0];
    const float* pos_p     = (const float*)d_in[1];
    const int*   ei_p      = (const int*)d_in[2];
    const int*   batch_p   = (const int*)d_in[3];
    const int*   residue_m = (const int*)d_in[4];
    const float* pos_m     = (const float*)d_in[5];
    const int*   ei_m      = (const int*)d_in[6];
    const int*   batch_m   = (const int*)d_in[7];
    const float* W_p1 = (const float*)d_in[8];
    const float* b_p1 = (const float*)d_in[9];
    const float* W_p2 = (const float*)d_in[10];
    const float* b_p2 = (const float*)d_in[11];
    const float* W_m1 = (const float*)d_in[12];
    const float* b_m1 = (const float*)d_in[13];
    const float* W_m2 = (const float*)d_in[14];
    const float* b_m2 = (const float*)d_in[15];
    const float* W1   = (const float*)d_in[16];
    const float* b1   = (const float*)d_in[17];
    const float* W2   = (const float*)d_in[18];
    const float* b2   = (const float*)d_in[19];

    const int N_P = in_sizes[0];
    const int E_P = in_sizes[2] / 2;
    const int N_M = in_sizes[4];
    const int E_M = in_sizes[6] / 2;
    const int G = 64;

    char* ws = (char*)d_ws;
    size_t off = 0;
    auto alloc = [&](size_t bytes) {
        char* p = ws + off;
        off += (bytes + 511) & ~size_t(511);
        return p;
    };
    f16*           y1h     = (f16*)  alloc((size_t)N_P * HID * 2);   // y1 = dinv*x1 fp16
    f16x4*         rec8    = (f16x4*)alloc((size_t)N_P * 8);
    unsigned char* res8    = (unsigned char*)alloc((size_t)N_P);
    float*         dinvA   = (float*)alloc((size_t)N_P * 4);
    int*           rowptr  = (int*)  alloc((size_t)(N_P + 1) * 4);
    int*           bcount  = (int*)  alloc((NBMAX + 1) * 4);
    int*           boff    = (int*)  alloc((NBMAX + 1) * 4);
    int*           bcursor = (int*)  alloc((NBMAX + 1) * 4);
    unsigned int*  pairs   = (unsigned int*)alloc((size_t)E_P * 4);
    int*           csr_src = (int*)  alloc((size_t)E_P * 4);
    float*         psum    = (float*)alloc((size_t)G * HID * 4);
    int*           pcnt    = (int*)  alloc((size_t)G * 4);
    float*         ctxW    = (float*)alloc((size_t)G * HID * 4);
    f16*           Wp2t    = (f16*)  alloc(128 * 128 * 2);
    f16*           Wm2t    = (f16*)  alloc(128 * 128 * 2);
    f16*           W1at    = (f16*)  alloc(128 * 128 * 2);

    k_prep_w<<<64, 256, 0, stream>>>(W_p2, W_m2, W1, Wp2t, Wm2t, W1at, bcount);
    k_graph_sizes<<<32, 256, 0, stream>>>(batch_p, pcnt, psum, N_P);

    auto build_graph = [&](const int* residue, const float* pos, const int* ei,
                           const float* Wl1, const float* bl1, int N, int E) {
        const int* srcp = ei;
        const int* dstp = ei + E;
        int NB = (N + 63) / 64;
        k_hist_bucket<<<256, 256, 0, stream>>>(dstp, bcount, E, NB);
        k_bucket_scan<<<1, 256, 0, stream>>>(bcount, bcount, boff, bcursor, NB);
        k_tile_bin<<<(E + BIN_T - 1) / BIN_T, 256, 0, stream>>>(srcp, dstp, bcursor, pairs, E, NB);
        k_bucket_fill2<<<NB, 256, 0, stream>>>(pairs, boff, residue, pos, csr_src,
                                               rec8, res8, dinvA, rowptr, N);
        k_l1_fused<<<NB, 256, 0, stream>>>(pairs, boff, rec8, res8, Wl1, bl1, dinvA, y1h, N);
    };

    // ---- protein branch ----
    build_graph(residue_p, pos_p, ei_p, W_p1, b_p1, N_P, E_P);
    k_agg_gemm_pool<<<(N_P + 63) / 64, 256, 0, stream>>>(y1h, rowptr, csr_src, dinvA,
                                                         Wp2t, b_p2, batch_p, psum, N_P);
    k_ctxw_div<<<G, HID, 0, stream>>>(psum, pcnt, W1, b1, ctxW);

    // ---- micromolecule branch ----
    build_graph(residue_m, pos_m, ei_m, W_m1, b_m1, N_M, E_M);
    k_agg_mm_tail<<<(N_M + 63) / 64, 256, 0, stream>>>(y1h, rowptr, csr_src, dinvA,
                                                       Wm2t, b_m2, batch_m, ctxW,
                                                       W1at, W2, b2, (float*)d_out, N_M);
}